// Round 6
// baseline (3350.991 us; speedup 1.0000x reference)
//
#include <hip/hip_runtime.h>
#include <hip/hip_cooperative_groups.h>

namespace cg = cooperative_groups;

#define NN 50000
#define NE 1600000
#define DIM 128
#define NG  512
#define NT  7            // src tiles of 8192 nodes (50000 >> 13 -> 0..6)
#define TSHIFT 13
#define NK  (NN * NT)    // 350000 sort keys
#define NBLK2 ((NK + 1023) / 1024)   // 342

#define CBLK 1024        // cooperative conv grid (4 blocks/CU guaranteed resident)
#define CWAVES (CBLK * 4)            // 4096 waves
#define NPW ((NN + CWAVES - 1) / CWAVES)   // 13 nodes per wave

typedef int      vint2   __attribute__((ext_vector_type(2)));
typedef float    vfloat4 __attribute__((ext_vector_type(4)));
typedef float    floatx4 __attribute__((ext_vector_type(4)));
typedef _Float16 half2v  __attribute__((ext_vector_type(2)));
typedef _Float16 half4v  __attribute__((ext_vector_type(4)));
typedef _Float16 half8   __attribute__((ext_vector_type(8)));

// ---------------- init: zero cnt2 + pooled ----------------
__global__ void init_kernel(int* __restrict__ cnt2, float* __restrict__ pooled) {
    int i = blockIdx.x * blockDim.x + threadIdx.x;
    int stride = gridDim.x * blockDim.x;
    for (int j = i; j < NK; j += stride) cnt2[j] = 0;
    for (int j = i; j < NG * DIM; j += stride) pooled[j] = 0.f;
}

// ---------------- count per (dst, src-tile) key ----------------
__global__ void count2_kernel(const int* __restrict__ src, const int* __restrict__ dst,
                              int* __restrict__ cnt2) {
    int e = blockIdx.x * blockDim.x + threadIdx.x;
    if (e >= NE) return;
    int s = __builtin_nontemporal_load(src + e);
    int d = __builtin_nontemporal_load(dst + e);
    atomicAdd(&cnt2[d * NT + (s >> TSHIFT)], 1);
}

// ---------------- scan phase 1: per-block local scan (1024 keys/block) ----------------
__global__ void scan1_kernel(const int* __restrict__ cnt2, int* __restrict__ lexcl,
                             int* __restrict__ bsum) {
    __shared__ int sd[1024];
    int t = threadIdx.x;
    int i = blockIdx.x * 1024 + t;
    int v = (i < NK) ? cnt2[i] : 0;
    sd[t] = v;
    __syncthreads();
    for (int off = 1; off < 1024; off <<= 1) {
        int add = (t >= off) ? sd[t - off] : 0;
        __syncthreads();
        sd[t] += add;
        __syncthreads();
    }
    int incl = sd[t];
    if (i < NK) lexcl[i] = incl - v;
    if (t == 1023) bsum[blockIdx.x] = incl;
}

// ---------------- scan phase 2: scan block sums (single 1024 block) ----------------
__global__ void scan2_kernel(const int* __restrict__ bsum, int* __restrict__ boffs,
                             int* __restrict__ rowp2) {
    __shared__ int sd[1024];
    int t = threadIdx.x;
    int v = (t < NBLK2) ? bsum[t] : 0;
    sd[t] = v;
    __syncthreads();
    for (int off = 1; off < 1024; off <<= 1) {
        int add = (t >= off) ? sd[t - off] : 0;
        __syncthreads();
        sd[t] += add;
        __syncthreads();
    }
    int incl = sd[t];
    if (t < NBLK2) boffs[t] = incl - v;
    if (t == 1023) rowp2[NK] = incl;   // grand total (== NE)
}

// ---------------- scan phase 3: global offsets ----------------
__global__ void scan3_kernel(const int* __restrict__ lexcl, const int* __restrict__ boffs,
                             int* __restrict__ rowp2, int* __restrict__ cursor2) {
    int i = blockIdx.x * 1024 + threadIdx.x;
    if (i < NK) {
        int v = lexcl[i] + boffs[blockIdx.x];
        rowp2[i] = v;
        cursor2[i] = v;
    }
}

// ---------------- per-node coeffs from rowp2 node boundaries ----------------
__global__ void coeff_kernel(const int* __restrict__ rowp2, float* __restrict__ disqrt,
                             float* __restrict__ selfn) {
    int i = blockIdx.x * blockDim.x + threadIdx.x;
    if (i >= NN) return;
    int deg = rowp2[(i + 1) * NT] - rowp2[i * NT];
    float dg = (float)(deg + 1);
    disqrt[i] = 1.0f / sqrtf(dg);
    selfn[i] = 1.0f / dg;
}

// ---------------- scatter edges into tiled CSR (packed {src, norm}) ----------------
__global__ void scatter_kernel(const int* __restrict__ src, const int* __restrict__ dst,
                               const float* __restrict__ disqrt, int* __restrict__ cursor2,
                               vint2* __restrict__ edges) {
    int e = blockIdx.x * blockDim.x + threadIdx.x;
    if (e >= NE) return;
    int s = __builtin_nontemporal_load(src + e);
    int d = __builtin_nontemporal_load(dst + e);
    float en = disqrt[s] * disqrt[d];
    int pos = atomicAdd(&cursor2[d * NT + (s >> TSHIFT)], 1);
    vint2 rec;
    rec.x = s;
    rec.y = __float_as_int(en);
    __builtin_nontemporal_store(rec, edges + pos);
}

// ---------------- convert x fp32 -> fp16 ----------------
__global__ void cvt_kernel(const float* __restrict__ x, _Float16* __restrict__ xh) {
    int i = blockIdx.x * 256 + threadIdx.x;   // one float4 per thread
    if (i >= NN * DIM / 4) return;
    vfloat4 v = ((const vfloat4*)x)[i];
    half4v o;
    o.x = (_Float16)v.x; o.y = (_Float16)v.y;
    o.z = (_Float16)v.z; o.w = (_Float16)v.w;
    ((half4v*)xh)[i] = o;
}

// ---------------- GEMM via MFMA: h[N,128](fp16) = y[N,128](fp16) @ W[128,128](fp32->fp16) --
__launch_bounds__(256, 2)
__global__ void gemm_mfma(const _Float16* __restrict__ yin, const float* __restrict__ W,
                          _Float16* __restrict__ hout) {
    __shared__ half8 Wf[2048];   // 4 ksteps x 8 ntiles x 64 lanes, 32 KB
    int tid = threadIdx.x;
    for (int idx = tid; idx < 2048; idx += 256) {
        int t = idx >> 9;
        int n = (idx >> 6) & 7;
        int ln = idx & 63;
        int q = ln >> 4, c = ln & 15;
        const float* wp = W + (t * 32 + q * 8) * DIM + n * 16 + c;
        half8 f;
#pragma unroll
        for (int j = 0; j < 8; ++j) f[j] = (_Float16)wp[j * DIM];
        Wf[idx] = f;
    }
    __syncthreads();
    int wid = tid >> 6, lane = tid & 63;
    int q = lane >> 4, m = lane & 15;
    const int ngroups = (NN + 63) / 64;   // 782
    for (int g = blockIdx.x; g < ngroups; g += gridDim.x) {
        int r0 = g * 64 + wid * 16;
        int arow = r0 + m;
        if (arow > NN - 1) arow = NN - 1;      // clamp; corrupt rows never stored
        const half8* ap = (const half8*)(yin + (size_t)arow * DIM + q * 8);
        half8 a0 = ap[0], a1 = ap[4], a2 = ap[8], a3 = ap[12];   // k += 32 per step
        floatx4 acc[8];
#pragma unroll
        for (int n = 0; n < 8; ++n) acc[n] = (floatx4){0.f, 0.f, 0.f, 0.f};
#pragma unroll
        for (int n = 0; n < 8; ++n)
            acc[n] = __builtin_amdgcn_mfma_f32_16x16x32_f16(a0, Wf[(0 * 8 + n) * 64 + lane], acc[n], 0, 0, 0);
#pragma unroll
        for (int n = 0; n < 8; ++n)
            acc[n] = __builtin_amdgcn_mfma_f32_16x16x32_f16(a1, Wf[(1 * 8 + n) * 64 + lane], acc[n], 0, 0, 0);
#pragma unroll
        for (int n = 0; n < 8; ++n)
            acc[n] = __builtin_amdgcn_mfma_f32_16x16x32_f16(a2, Wf[(2 * 8 + n) * 64 + lane], acc[n], 0, 0, 0);
#pragma unroll
        for (int n = 0; n < 8; ++n)
            acc[n] = __builtin_amdgcn_mfma_f32_16x16x32_f16(a3, Wf[(3 * 8 + n) * 64 + lane], acc[n], 0, 0, 0);
#pragma unroll
        for (int n = 0; n < 8; ++n) {
#pragma unroll
            for (int r = 0; r < 4; ++r) {
                int row = r0 + q * 4 + r;
                if (row < NN)
                    hout[(size_t)row * DIM + n * 16 + m] = (_Float16)acc[n][r];
            }
        }
    }
}

// ---------------- cooperative fused conv: tile-phased gather + epilogue ----------------
// 1024 blocks x 4 waves; wave owns NPW consecutive nodes; per-node partials in
// private LDS slots (each thread touches only its own slots -> no syncs needed).
// grid.sync() between src-tile phases keeps every XCD's gather working set = one
// 2 MB tile -> fits 4 MB per-XCD L2.
__launch_bounds__(256, 4)
__global__ void conv_coop(const half2v* __restrict__ h2, const float* __restrict__ bias,
                          const int* __restrict__ rowp2, const vint2* __restrict__ edges,
                          const float* __restrict__ selfn, half2v* __restrict__ out,
                          const int* __restrict__ batch, float* __restrict__ pooled,
                          int do_pool) {
    __shared__ float sAx[NPW * 256];
    __shared__ float sAy[NPW * 256];
    cg::grid_group grid = cg::this_grid();
    int tid = threadIdx.x;
    int wid = tid >> 6;
    int lane = tid & 63;
    int W = blockIdx.x * 4 + wid;       // global wave id, 0..CWAVES-1
    int n0 = W * NPW;                   // first node owned by this wave

#pragma unroll
    for (int i = 0; i < NPW; ++i) { sAx[i * 256 + tid] = 0.f; sAy[i * 256 + tid] = 0.f; }

    for (int t = 0; t < NT; ++t) {
        for (int i = 0; i < NPW; ++i) {
            int node = n0 + i;
            if (node < NN) {
                int base = node * NT + t;
                int beg = rowp2[base], end = rowp2[base + 1];
                float ax = 0.f, ay = 0.f;
                int e = beg;
                for (; e + 4 <= end; e += 4) {
                    vint2 r0 = __builtin_nontemporal_load(edges + e);
                    vint2 r1 = __builtin_nontemporal_load(edges + e + 1);
                    vint2 r2 = __builtin_nontemporal_load(edges + e + 2);
                    vint2 r3 = __builtin_nontemporal_load(edges + e + 3);
                    half2v v0 = h2[(size_t)r0.x * 64 + lane];
                    half2v v1 = h2[(size_t)r1.x * 64 + lane];
                    half2v v2 = h2[(size_t)r2.x * 64 + lane];
                    half2v v3 = h2[(size_t)r3.x * 64 + lane];
                    float w0 = __int_as_float(r0.y), w1 = __int_as_float(r1.y);
                    float w2 = __int_as_float(r2.y), w3 = __int_as_float(r3.y);
                    ax += w0 * (float)v0.x + w1 * (float)v1.x + w2 * (float)v2.x + w3 * (float)v3.x;
                    ay += w0 * (float)v0.y + w1 * (float)v1.y + w2 * (float)v2.y + w3 * (float)v3.y;
                }
                for (; e < end; ++e) {
                    vint2 r = __builtin_nontemporal_load(edges + e);
                    half2v v = h2[(size_t)r.x * 64 + lane];
                    float w = __int_as_float(r.y);
                    ax += w * (float)v.x;
                    ay += w * (float)v.y;
                }
                sAx[i * 256 + tid] += ax;
                sAy[i * 256 + tid] += ay;
            }
        }
        if (t < NT - 1) grid.sync();
    }

    // epilogue: self term + bias + L2-normalize + ReLU (+pool)
    float bx = bias[2 * lane];
    float by = bias[2 * lane + 1];
    for (int i = 0; i < NPW; ++i) {
        int node = n0 + i;
        if (node >= NN) continue;
        float ax = sAx[i * 256 + tid];
        float ay = sAy[i * 256 + tid];
        float sn = selfn[node];
        half2v hv = h2[(size_t)node * 64 + lane];
        ax += sn * (float)hv.x + bx;
        ay += sn * (float)hv.y + by;
        float ss = ax * ax + ay * ay;
#pragma unroll
        for (int off = 32; off; off >>= 1) ss += __shfl_xor(ss, off);
        float inv = 1.0f / fmaxf(sqrtf(ss), 1e-12f);
        float ox = fmaxf(ax * inv, 0.f);
        float oy = fmaxf(ay * inv, 0.f);
        if (!do_pool) {
            half2v o;
            o.x = (_Float16)ox;
            o.y = (_Float16)oy;
            out[(size_t)node * 64 + lane] = o;   // cached store: y stays L2-hot for GEMM
        } else {
            int g = batch[node];
            atomicAdd(&pooled[g * DIM + 2 * lane], ox);
            atomicAdd(&pooled[g * DIM + 2 * lane + 1], oy);
        }
    }
}

// ---------------- head: z = relu(pooled@W1+b1); logits = z@W2+b2 ----------------
__launch_bounds__(128)
__global__ void head_kernel(const float* __restrict__ pooled, const float* __restrict__ w1,
                            const float* __restrict__ b1, const float* __restrict__ w2,
                            const float* __restrict__ b2, float* __restrict__ out) {
    __shared__ float sp[DIM];
    __shared__ float red[4];
    int g = blockIdx.x;
    int k = threadIdx.x;
    sp[k] = pooled[g * DIM + k];
    __syncthreads();
    float acc = b1[k];
#pragma unroll 8
    for (int j = 0; j < DIM; ++j) acc += sp[j] * w1[j * DIM + k];
    float z = fmaxf(acc, 0.f);
    float p0 = z * w2[k * 2 + 0];
    float p1 = z * w2[k * 2 + 1];
#pragma unroll
    for (int off = 32; off; off >>= 1) {
        p0 += __shfl_xor(p0, off);
        p1 += __shfl_xor(p1, off);
    }
    if ((k & 63) == 0) {
        red[(k >> 6) * 2 + 0] = p0;
        red[(k >> 6) * 2 + 1] = p1;
    }
    __syncthreads();
    if (k == 0) {
        out[g * 2 + 0] = red[0] + red[2] + b2[0];
        out[g * 2 + 1] = red[1] + red[3] + b2[1];
    }
}

extern "C" void kernel_launch(void* const* d_in, const int* in_sizes, int n_in,
                              void* d_out, int out_size, void* d_ws, size_t ws_size,
                              hipStream_t stream) {
    const float* x    = (const float*)d_in[0];
    const int* eidx   = (const int*)d_in[1];
    const int* batch  = (const int*)d_in[2];
    const float* W0   = (const float*)d_in[3];
    const float* b0   = (const float*)d_in[4];
    const float* W1   = (const float*)d_in[5];
    const float* b1   = (const float*)d_in[6];
    const float* W2   = (const float*)d_in[7];
    const float* b2   = (const float*)d_in[8];
    const float* l1w  = (const float*)d_in[9];
    const float* l1b  = (const float*)d_in[10];
    const float* l2w  = (const float*)d_in[11];
    const float* l2b  = (const float*)d_in[12];
    float* out = (float*)d_out;

    char* w = (char*)d_ws;
    float* disqrt = (float*)w; w += (size_t)NN * 4;
    float* selfn  = (float*)w; w += (size_t)NN * 4;
    int*   cnt2   = (int*)w;   w += (size_t)NK * 4;
    int*   rowp2  = (int*)w;   w += (size_t)(NK + 8) * 4;
    int*   cursor2= (int*)w;   w += (size_t)NK * 4;
    int*   lexcl  = (int*)w;   w += (size_t)NK * 4;
    int*   bsum   = (int*)w;   w += 1024 * 4;
    int*   boffs  = (int*)w;   w += 1024 * 4;
    vint2* edges  = (vint2*)w; w += (size_t)NE * 8;
    _Float16* xh  = (_Float16*)w; w += (size_t)NN * DIM * 2;
    _Float16* bufh = (_Float16*)w; w += (size_t)NN * DIM * 2;   // h (GEMM out, gathered)
    _Float16* bufy = (_Float16*)w; w += (size_t)NN * DIM * 2;   // y (conv out)
    float* pooled = (float*)w; w += (size_t)NG * DIM * 4;

    const int* src = eidx;
    const int* dst = eidx + NE;

    init_kernel<<<512, 256, 0, stream>>>(cnt2, pooled);
    count2_kernel<<<(NE + 255) / 256, 256, 0, stream>>>(src, dst, cnt2);
    scan1_kernel<<<NBLK2, 1024, 0, stream>>>(cnt2, lexcl, bsum);
    scan2_kernel<<<1, 1024, 0, stream>>>(bsum, boffs, rowp2);
    scan3_kernel<<<NBLK2, 1024, 0, stream>>>(lexcl, boffs, rowp2, cursor2);
    coeff_kernel<<<(NN + 255) / 256, 256, 0, stream>>>(rowp2, disqrt, selfn);
    scatter_kernel<<<(NE + 255) / 256, 256, 0, stream>>>(src, dst, disqrt, cursor2, edges);

    cvt_kernel<<<(NN * DIM / 4 + 255) / 256, 256, 0, stream>>>(x, xh);

    const half2v* hc;
    half2v* yc;
    const float* bp;
    int dp;
    void* cargs[9];
    cargs[0] = &hc; cargs[1] = &bp; cargs[2] = (void*)&rowp2; cargs[3] = (void*)&edges;
    cargs[4] = (void*)&selfn; cargs[5] = &yc; cargs[6] = (void*)&batch;
    cargs[7] = (void*)&pooled; cargs[8] = &dp;

    gemm_mfma<<<256, 256, 0, stream>>>(xh, W0, bufh);
    hc = (const half2v*)bufh; yc = (half2v*)bufy; bp = b0; dp = 0;
    hipLaunchCooperativeKernel((const void*)conv_coop, dim3(CBLK), dim3(256), cargs, 0, stream);

    gemm_mfma<<<256, 256, 0, stream>>>(bufy, W1, bufh);
    hc = (const half2v*)bufh; yc = (half2v*)bufy; bp = b1; dp = 0;
    hipLaunchCooperativeKernel((const void*)conv_coop, dim3(CBLK), dim3(256), cargs, 0, stream);

    gemm_mfma<<<256, 256, 0, stream>>>(bufy, W2, bufh);
    hc = (const half2v*)bufh; yc = (half2v*)bufy; bp = b2; dp = 1;
    hipLaunchCooperativeKernel((const void*)conv_coop, dim3(CBLK), dim3(256), cargs, 0, stream);

    head_kernel<<<NG, 128, 0, stream>>>(pooled, l1w, l1b, l2w, l2b, out);
}

// Round 7
// 816.313 us; speedup vs baseline: 4.1050x; 4.1050x over previous
//
#include <hip/hip_runtime.h>

#define NN 50000
#define NE 1600000
#define DIM 128
#define NG  512
#define NBLK 49        // ceil(NN/1024)

typedef float    vfloat4 __attribute__((ext_vector_type(4)));
typedef float    floatx4 __attribute__((ext_vector_type(4)));
typedef _Float16 half2v  __attribute__((ext_vector_type(2)));
typedef _Float16 half4v  __attribute__((ext_vector_type(4)));
typedef _Float16 half8   __attribute__((ext_vector_type(8)));

__device__ __forceinline__ float hbits2f(unsigned u) {
    union { unsigned short us; _Float16 h; } c;
    c.us = (unsigned short)u;
    return (float)c.h;
}

// ---------------- init: zero cnt + pooled ----------------
__global__ void init_kernel(int* __restrict__ cnt, float* __restrict__ pooled) {
    int i = blockIdx.x * blockDim.x + threadIdx.x;
    int stride = gridDim.x * blockDim.x;
    for (int j = i; j < NN; j += stride) cnt[j] = 0;
    for (int j = i; j < NG * DIM; j += stride) pooled[j] = 0.f;
}

// ---------------- in-degree count (by dst) ----------------
__global__ void count_kernel(const int* __restrict__ dst, int* __restrict__ cnt) {
    int e = blockIdx.x * blockDim.x + threadIdx.x;
    if (e < NE) atomicAdd(&cnt[__builtin_nontemporal_load(dst + e)], 1);
}

// ---------------- scan phase 1: per-block local scan + coeffs ----------------
__global__ void scan1_kernel(const int* __restrict__ cnt, int* __restrict__ lexcl,
                             int* __restrict__ bsum, float* __restrict__ disqrt,
                             float* __restrict__ selfn) {
    __shared__ int sd[1024];
    int t = threadIdx.x;
    int i = blockIdx.x * 1024 + t;
    int v = (i < NN) ? cnt[i] : 0;
    sd[t] = v;
    __syncthreads();
    for (int off = 1; off < 1024; off <<= 1) {
        int add = (t >= off) ? sd[t - off] : 0;
        __syncthreads();
        sd[t] += add;
        __syncthreads();
    }
    int incl = sd[t];
    if (i < NN) {
        lexcl[i] = incl - v;
        float dg = (float)(v + 1);
        disqrt[i] = 1.0f / sqrtf(dg);
        selfn[i] = 1.0f / dg;
    }
    if (t == 1023) bsum[blockIdx.x] = incl;
}

// ---------------- scan phase 2: scan block sums ----------------
__global__ void scan2_kernel(const int* __restrict__ bsum, int* __restrict__ boffs,
                             int* __restrict__ rowp) {
    __shared__ int sd[1024];
    int t = threadIdx.x;
    int v = (t < NBLK) ? bsum[t] : 0;
    sd[t] = v;
    __syncthreads();
    for (int off = 1; off < 1024; off <<= 1) {
        int add = (t >= off) ? sd[t - off] : 0;
        __syncthreads();
        sd[t] += add;
        __syncthreads();
    }
    int incl = sd[t];
    if (t < NBLK) boffs[t] = incl - v;
    if (t == 1023) rowp[NN] = incl;   // grand total (== NE)
}

// ---------------- scan phase 3: global offsets ----------------
__global__ void scan3_kernel(const int* __restrict__ lexcl, const int* __restrict__ boffs,
                             int* __restrict__ rowp, int* __restrict__ cursor) {
    int i = blockIdx.x * 1024 + threadIdx.x;
    if (i < NN) {
        int v = lexcl[i] + boffs[blockIdx.x];
        rowp[i] = v;
        cursor[i] = v;
    }
}

// ---------------- scatter edges into CSR: packed 4B {src:u16, norm:f16} ----------------
__global__ void scatter_kernel(const int* __restrict__ src, const int* __restrict__ dst,
                               const float* __restrict__ disqrt, int* __restrict__ cursor,
                               unsigned* __restrict__ edges) {
    int e = blockIdx.x * blockDim.x + threadIdx.x;
    if (e >= NE) return;
    int s = __builtin_nontemporal_load(src + e);
    int d = __builtin_nontemporal_load(dst + e);
    float en = disqrt[s] * disqrt[d];
    union { _Float16 h; unsigned short us; } c;
    c.h = (_Float16)en;
    unsigned rec = (unsigned)s | ((unsigned)c.us << 16);   // NN < 65536
    int pos = atomicAdd(&cursor[d], 1);
    __builtin_nontemporal_store(rec, edges + pos);
}

// ---------------- convert x fp32 -> fp16 ----------------
__global__ void cvt_kernel(const float* __restrict__ x, _Float16* __restrict__ xh) {
    int i = blockIdx.x * 256 + threadIdx.x;   // one float4 per thread
    if (i >= NN * DIM / 4) return;
    vfloat4 v = ((const vfloat4*)x)[i];
    half4v o;
    o.x = (_Float16)v.x; o.y = (_Float16)v.y;
    o.z = (_Float16)v.z; o.w = (_Float16)v.w;
    ((half4v*)xh)[i] = o;
}

// ---------------- pre-convert W (fp32 [128][128]) to B-frag half8 layout ----------------
// layout idx = t*512 + n*64 + lane; elem j = W[(t*32 + (lane>>4)*8 + j)*128 + n*16 + (lane&15)]
__global__ void cvtw_kernel(const float* __restrict__ W0, const float* __restrict__ W1,
                            const float* __restrict__ W2, half8* __restrict__ wf) {
    const float* Ws[3] = {W0, W1, W2};
    const float* W = Ws[blockIdx.x];
    half8* out = wf + (size_t)blockIdx.x * 2048;
    for (int idx = threadIdx.x; idx < 2048; idx += 256) {
        int t = idx >> 9;
        int n = (idx >> 6) & 7;
        int ln = idx & 63;
        int q = ln >> 4, c = ln & 15;
        const float* wp = W + (t * 32 + q * 8) * DIM + n * 16 + c;
        half8 f;
#pragma unroll
        for (int j = 0; j < 8; ++j) f[j] = (_Float16)wp[j * DIM];
        out[idx] = f;
    }
}

// ---------------- GEMM via MFMA, fused input relu*inv_norm ----------------
// h[N,128](fp16) = act(y[N,128]) @ Wf ; act = identity (invn==null) or relu(.)*invn[row]
__launch_bounds__(256, 2)
__global__ void gemm_mfma(const _Float16* __restrict__ yin, const half8* __restrict__ wfl,
                          const float* __restrict__ invn, _Float16* __restrict__ hout) {
    __shared__ half8 Wf[2048];   // 32 KB
    int tid = threadIdx.x;
    for (int idx = tid; idx < 2048; idx += 256) Wf[idx] = wfl[idx];
    __syncthreads();
    int wid = tid >> 6, lane = tid & 63;
    int q = lane >> 4, m = lane & 15;
    const int ngroups = (NN + 63) / 64;   // 782
    for (int g = blockIdx.x; g < ngroups; g += gridDim.x) {
        int r0 = g * 64 + wid * 16;
        int arow = r0 + m;
        if (arow > NN - 1) arow = NN - 1;      // clamp; clamped rows never stored
        const half8* ap = (const half8*)(yin + (size_t)arow * DIM + q * 8);
        half8 a0 = ap[0], a1 = ap[4], a2 = ap[8], a3 = ap[12];   // k += 32 per step
        if (invn) {
            _Float16 iv = (_Float16)invn[arow];
            const _Float16 z = (_Float16)0.f;
#pragma unroll
            for (int j = 0; j < 8; ++j) {
                a0[j] = (a0[j] > z ? a0[j] : z) * iv;
                a1[j] = (a1[j] > z ? a1[j] : z) * iv;
                a2[j] = (a2[j] > z ? a2[j] : z) * iv;
                a3[j] = (a3[j] > z ? a3[j] : z) * iv;
            }
        }
        floatx4 acc[8];
#pragma unroll
        for (int n = 0; n < 8; ++n) acc[n] = (floatx4){0.f, 0.f, 0.f, 0.f};
#pragma unroll
        for (int n = 0; n < 8; ++n)
            acc[n] = __builtin_amdgcn_mfma_f32_16x16x32_f16(a0, Wf[(0 * 8 + n) * 64 + lane], acc[n], 0, 0, 0);
#pragma unroll
        for (int n = 0; n < 8; ++n)
            acc[n] = __builtin_amdgcn_mfma_f32_16x16x32_f16(a1, Wf[(1 * 8 + n) * 64 + lane], acc[n], 0, 0, 0);
#pragma unroll
        for (int n = 0; n < 8; ++n)
            acc[n] = __builtin_amdgcn_mfma_f32_16x16x32_f16(a2, Wf[(2 * 8 + n) * 64 + lane], acc[n], 0, 0, 0);
#pragma unroll
        for (int n = 0; n < 8; ++n)
            acc[n] = __builtin_amdgcn_mfma_f32_16x16x32_f16(a3, Wf[(3 * 8 + n) * 64 + lane], acc[n], 0, 0, 0);
#pragma unroll
        for (int n = 0; n < 8; ++n) {
#pragma unroll
            for (int r = 0; r < 4; ++r) {
                int row = r0 + q * 4 + r;
                if (row < NN)
                    hout[(size_t)row * DIM + n * 16 + m] = (_Float16)acc[n][r];
            }
        }
    }
}

// ---------------- conv pass: 64-col half-feature aggregation ----------------
// One wave per node; lane handles col fo+lane (2B gather => 128B/line full util,
// working set 6.4 MB vs 4 MB/XCD L2). Writes PRE-norm y (fp16) + ssq (pass 0)
// or inv_norm (pass 1). Normalize+relu folds into the next gemm's A-load.
__launch_bounds__(256, 8)
__global__ void conv_pass(const _Float16* __restrict__ h, const float* __restrict__ bias,
                          const int* __restrict__ rowp, const unsigned* __restrict__ edges,
                          const float* __restrict__ selfn, _Float16* __restrict__ y,
                          float* __restrict__ ssq, float* __restrict__ invn, int fo) {
    int wid = threadIdx.x >> 6;
    int lane = threadIdx.x & 63;
    int node = blockIdx.x * 4 + wid;
    if (node >= NN) return;
    int col = fo + lane;
    const _Float16* hp = h + col;     // gather base for this lane's column
    int beg = rowp[node], end = rowp[node + 1];
    float a = 0.f;
    int e = beg;
    for (; e + 4 <= end; e += 4) {
        unsigned r0 = __builtin_nontemporal_load(edges + e);
        unsigned r1 = __builtin_nontemporal_load(edges + e + 1);
        unsigned r2 = __builtin_nontemporal_load(edges + e + 2);
        unsigned r3 = __builtin_nontemporal_load(edges + e + 3);
        _Float16 v0 = hp[(size_t)(r0 & 0xFFFFu) << 7];
        _Float16 v1 = hp[(size_t)(r1 & 0xFFFFu) << 7];
        _Float16 v2 = hp[(size_t)(r2 & 0xFFFFu) << 7];
        _Float16 v3 = hp[(size_t)(r3 & 0xFFFFu) << 7];
        a += hbits2f(r0 >> 16) * (float)v0 + hbits2f(r1 >> 16) * (float)v1
           + hbits2f(r2 >> 16) * (float)v2 + hbits2f(r3 >> 16) * (float)v3;
    }
    for (; e < end; ++e) {
        unsigned r = __builtin_nontemporal_load(edges + e);
        _Float16 v = hp[(size_t)(r & 0xFFFFu) << 7];
        a += hbits2f(r >> 16) * (float)v;
    }
    a += selfn[node] * (float)hp[(size_t)node << 7] + bias[col];
    // full-wave sum of squares for this half
    float ss = a * a;
#pragma unroll
    for (int off = 32; off; off >>= 1) ss += __shfl_xor(ss, off);
    y[(size_t)node * DIM + col] = (_Float16)a;   // pre-norm, cached (gemm reads next)
    if (fo == 0) {
        if (lane == 0) ssq[node] = ss;
    } else {
        float tot = ss + ssq[node];
        if (lane == 0) invn[node] = 1.0f / fmaxf(sqrtf(tot), 1e-12f);
    }
}

// ---------------- layer-3 epilogue: normalize + relu + pool ----------------
__launch_bounds__(256, 8)
__global__ void epi3_kernel(const half2v* __restrict__ y2, const float* __restrict__ invn,
                            const int* __restrict__ batch, float* __restrict__ pooled) {
    int wid = threadIdx.x >> 6;
    int lane = threadIdx.x & 63;
    int node = blockIdx.x * 4 + wid;
    if (node >= NN) return;
    half2v v = y2[(size_t)node * 64 + lane];
    float inv = invn[node];
    float ox = fmaxf((float)v.x * inv, 0.f);
    float oy = fmaxf((float)v.y * inv, 0.f);
    int g = batch[node];
    atomicAdd(&pooled[g * DIM + 2 * lane], ox);
    atomicAdd(&pooled[g * DIM + 2 * lane + 1], oy);
}

// ---------------- head: z = relu(pooled@W1+b1); logits = z@W2+b2 ----------------
__launch_bounds__(128)
__global__ void head_kernel(const float* __restrict__ pooled, const float* __restrict__ w1,
                            const float* __restrict__ b1, const float* __restrict__ w2,
                            const float* __restrict__ b2, float* __restrict__ out) {
    __shared__ float sp[DIM];
    __shared__ float red[4];
    int g = blockIdx.x;
    int k = threadIdx.x;
    sp[k] = pooled[g * DIM + k];
    __syncthreads();
    float acc = b1[k];
#pragma unroll 8
    for (int j = 0; j < DIM; ++j) acc += sp[j] * w1[j * DIM + k];
    float z = fmaxf(acc, 0.f);
    float p0 = z * w2[k * 2 + 0];
    float p1 = z * w2[k * 2 + 1];
#pragma unroll
    for (int off = 32; off; off >>= 1) {
        p0 += __shfl_xor(p0, off);
        p1 += __shfl_xor(p1, off);
    }
    if ((k & 63) == 0) {
        red[(k >> 6) * 2 + 0] = p0;
        red[(k >> 6) * 2 + 1] = p1;
    }
    __syncthreads();
    if (k == 0) {
        out[g * 2 + 0] = red[0] + red[2] + b2[0];
        out[g * 2 + 1] = red[1] + red[3] + b2[1];
    }
}

extern "C" void kernel_launch(void* const* d_in, const int* in_sizes, int n_in,
                              void* d_out, int out_size, void* d_ws, size_t ws_size,
                              hipStream_t stream) {
    const float* x    = (const float*)d_in[0];
    const int* eidx   = (const int*)d_in[1];
    const int* batch  = (const int*)d_in[2];
    const float* W0   = (const float*)d_in[3];
    const float* b0   = (const float*)d_in[4];
    const float* W1   = (const float*)d_in[5];
    const float* b1   = (const float*)d_in[6];
    const float* W2   = (const float*)d_in[7];
    const float* b2   = (const float*)d_in[8];
    const float* l1w  = (const float*)d_in[9];
    const float* l1b  = (const float*)d_in[10];
    const float* l2w  = (const float*)d_in[11];
    const float* l2b  = (const float*)d_in[12];
    float* out = (float*)d_out;

    char* w = (char*)d_ws;
    float* disqrt = (float*)w; w += (size_t)NN * 4;
    float* selfn  = (float*)w; w += (size_t)NN * 4;
    float* ssq    = (float*)w; w += (size_t)NN * 4;
    float* invn   = (float*)w; w += (size_t)NN * 4;
    int*   cnt    = (int*)w;   w += (size_t)NN * 4;
    int*   rowp   = (int*)w;   w += (size_t)(NN + 8) * 4;
    int*   cursor = (int*)w;   w += (size_t)NN * 4;
    int*   lexcl  = (int*)w;   w += (size_t)NN * 4;
    int*   bsum   = (int*)w;   w += 1024 * 4;
    int*   boffs  = (int*)w;   w += 1024 * 4;
    unsigned* edges = (unsigned*)w; w += (size_t)NE * 4;
    half8* wf     = (half8*)w; w += (size_t)3 * 2048 * 16;
    _Float16* xh  = (_Float16*)w; w += (size_t)NN * DIM * 2;
    _Float16* bufh = (_Float16*)w; w += (size_t)NN * DIM * 2;   // h (gemm out, gathered)
    _Float16* bufy = (_Float16*)w; w += (size_t)NN * DIM * 2;   // y (conv out, pre-norm)
    float* pooled = (float*)w; w += (size_t)NG * DIM * 4;

    const int* src = eidx;
    const int* dst = eidx + NE;

    init_kernel<<<256, 256, 0, stream>>>(cnt, pooled);
    count_kernel<<<(NE + 255) / 256, 256, 0, stream>>>(dst, cnt);
    scan1_kernel<<<NBLK, 1024, 0, stream>>>(cnt, lexcl, bsum, disqrt, selfn);
    scan2_kernel<<<1, 1024, 0, stream>>>(bsum, boffs, rowp);
    scan3_kernel<<<NBLK, 1024, 0, stream>>>(lexcl, boffs, rowp, cursor);
    scatter_kernel<<<(NE + 255) / 256, 256, 0, stream>>>(src, dst, disqrt, cursor, edges);
    cvt_kernel<<<(NN * DIM / 4 + 255) / 256, 256, 0, stream>>>(x, xh);
    cvtw_kernel<<<3, 256, 0, stream>>>(W0, W1, W2, wf);

    const int CG = (NN + 3) / 4;   // 12500 blocks, one wave per node

    gemm_mfma<<<512, 256, 0, stream>>>(xh, wf, nullptr, bufh);
    conv_pass<<<CG, 256, 0, stream>>>(bufh, b0, rowp, edges, selfn, bufy, ssq, invn, 0);
    conv_pass<<<CG, 256, 0, stream>>>(bufh, b0, rowp, edges, selfn, bufy, ssq, invn, 64);

    gemm_mfma<<<512, 256, 0, stream>>>(bufy, wf + 2048, invn, bufh);
    conv_pass<<<CG, 256, 0, stream>>>(bufh, b1, rowp, edges, selfn, bufy, ssq, invn, 0);
    conv_pass<<<CG, 256, 0, stream>>>(bufh, b1, rowp, edges, selfn, bufy, ssq, invn, 64);

    gemm_mfma<<<512, 256, 0, stream>>>(bufy, wf + 4096, invn, bufh);
    conv_pass<<<CG, 256, 0, stream>>>(bufh, b2, rowp, edges, selfn, bufy, ssq, invn, 0);
    conv_pass<<<CG, 256, 0, stream>>>(bufh, b2, rowp, edges, selfn, bufy, ssq, invn, 64);

    epi3_kernel<<<CG, 256, 0, stream>>>((const half2v*)bufy, invn, batch, pooled);
    head_kernel<<<NG, 128, 0, stream>>>(pooled, l1w, l1b, l2w, l2b, out);
}

// Round 8
// 582.983 us; speedup vs baseline: 5.7480x; 1.4002x over previous
//
#include <hip/hip_runtime.h>

#define NN 50000
#define NE 1600000
#define DIM 128
#define NG  512
#define NBLK 49        // ceil(NN/1024)
#define NPASS 4
#define PASSW 12500    // NN / NPASS

typedef float    vfloat4 __attribute__((ext_vector_type(4)));
typedef float    floatx4 __attribute__((ext_vector_type(4)));
typedef _Float16 half2v  __attribute__((ext_vector_type(2)));
typedef _Float16 half4v  __attribute__((ext_vector_type(4)));
typedef _Float16 half8   __attribute__((ext_vector_type(8)));

__device__ __forceinline__ float hbits2f(unsigned u) {
    union { unsigned short us; _Float16 h; } c;
    c.us = (unsigned short)u;
    return (float)c.h;
}

// ---------------- init: zero cnt + pooled ----------------
__global__ void init_kernel(int* __restrict__ cnt, float* __restrict__ pooled) {
    int i = blockIdx.x * blockDim.x + threadIdx.x;
    int stride = gridDim.x * blockDim.x;
    for (int j = i; j < NN; j += stride) cnt[j] = 0;
    for (int j = i; j < NG * DIM; j += stride) pooled[j] = 0.f;
}

// ---------------- in-degree count (by dst) ----------------
__global__ void count_kernel(const int* __restrict__ dst, int* __restrict__ cnt) {
    int e = blockIdx.x * blockDim.x + threadIdx.x;
    if (e < NE) atomicAdd(&cnt[dst[e]], 1);
}

// ---------------- scan phase 1: per-block local scan + coeffs ----------------
__global__ void scan1_kernel(const int* __restrict__ cnt, int* __restrict__ lexcl,
                             int* __restrict__ bsum, float* __restrict__ disqrt,
                             float* __restrict__ selfn) {
    __shared__ int sd[1024];
    int t = threadIdx.x;
    int i = blockIdx.x * 1024 + t;
    int v = (i < NN) ? cnt[i] : 0;
    sd[t] = v;
    __syncthreads();
    for (int off = 1; off < 1024; off <<= 1) {
        int add = (t >= off) ? sd[t - off] : 0;
        __syncthreads();
        sd[t] += add;
        __syncthreads();
    }
    int incl = sd[t];
    if (i < NN) {
        lexcl[i] = incl - v;
        float dg = (float)(v + 1);
        disqrt[i] = 1.0f / sqrtf(dg);
        selfn[i] = 1.0f / dg;
    }
    if (t == 1023) bsum[blockIdx.x] = incl;
}

// ---------------- scan phase 2: scan block sums ----------------
__global__ void scan2_kernel(const int* __restrict__ bsum, int* __restrict__ boffs,
                             int* __restrict__ rowp) {
    __shared__ int sd[1024];
    int t = threadIdx.x;
    int v = (t < NBLK) ? bsum[t] : 0;
    sd[t] = v;
    __syncthreads();
    for (int off = 1; off < 1024; off <<= 1) {
        int add = (t >= off) ? sd[t - off] : 0;
        __syncthreads();
        sd[t] += add;
        __syncthreads();
    }
    int incl = sd[t];
    if (t < NBLK) boffs[t] = incl - v;
    if (t == 1023) rowp[NN] = incl;   // grand total (== NE)
}

// ---------------- scan phase 3: global offsets ----------------
__global__ void scan3_kernel(const int* __restrict__ lexcl, const int* __restrict__ boffs,
                             int* __restrict__ rowp, int* __restrict__ cursor) {
    int i = blockIdx.x * 1024 + threadIdx.x;
    if (i < NN) {
        int v = lexcl[i] + boffs[blockIdx.x];
        rowp[i] = v;
        cursor[i] = v;
    }
}

// ---------------- scatter pass: only edges with dst in [lo,hi) ----------------
// Writes land in a contiguous ~1.6 MB region -> lines stay L2-resident and
// coalesce (16 records/line) before write-back. Cached stores on purpose.
__global__ void scatter_kernel(const int* __restrict__ src, const int* __restrict__ dst,
                               const float* __restrict__ disqrt, int* __restrict__ cursor,
                               unsigned* __restrict__ edges, int lo, int hi) {
    int e = blockIdx.x * blockDim.x + threadIdx.x;
    if (e >= NE) return;
    int d = dst[e];
    if (d < lo || d >= hi) return;
    int s = src[e];
    float en = disqrt[s] * disqrt[d];
    union { _Float16 h; unsigned short us; } c;
    c.h = (_Float16)en;
    unsigned rec = (unsigned)s | ((unsigned)c.us << 16);   // NN < 65536
    int pos = atomicAdd(&cursor[d], 1);
    edges[pos] = rec;
}

// ---------------- convert x fp32 -> fp16 ----------------
__global__ void cvt_kernel(const float* __restrict__ x, _Float16* __restrict__ xh) {
    int i = blockIdx.x * 256 + threadIdx.x;   // one float4 per thread
    if (i >= NN * DIM / 4) return;
    vfloat4 v = ((const vfloat4*)x)[i];
    half4v o;
    o.x = (_Float16)v.x; o.y = (_Float16)v.y;
    o.z = (_Float16)v.z; o.w = (_Float16)v.w;
    ((half4v*)xh)[i] = o;
}

// ---------------- pre-convert W (fp32 [128][128]) to B-frag half8 layout ----------------
__global__ void cvtw_kernel(const float* __restrict__ W0, const float* __restrict__ W1,
                            const float* __restrict__ W2, half8* __restrict__ wf) {
    const float* Ws[3] = {W0, W1, W2};
    const float* W = Ws[blockIdx.x];
    half8* out = wf + (size_t)blockIdx.x * 2048;
    for (int idx = threadIdx.x; idx < 2048; idx += 256) {
        int t = idx >> 9;
        int n = (idx >> 6) & 7;
        int ln = idx & 63;
        int q = ln >> 4, c = ln & 15;
        const float* wp = W + (t * 32 + q * 8) * DIM + n * 16 + c;
        half8 f;
#pragma unroll
        for (int j = 0; j < 8; ++j) f[j] = (_Float16)wp[j * DIM];
        out[idx] = f;
    }
}

// ---------------- GEMM via MFMA: one 64-row group per block ----------------
__launch_bounds__(256, 2)
__global__ void gemm_mfma(const _Float16* __restrict__ yin, const half8* __restrict__ wfl,
                          _Float16* __restrict__ hout) {
    __shared__ half8 Wf[2048];   // 32 KB
    int tid = threadIdx.x;
    for (int idx = tid; idx < 2048; idx += 256) Wf[idx] = wfl[idx];
    __syncthreads();
    int wid = tid >> 6, lane = tid & 63;
    int q = lane >> 4, m = lane & 15;
    int r0 = blockIdx.x * 64 + wid * 16;
    int arow = r0 + m;
    if (arow > NN - 1) arow = NN - 1;      // clamp; clamped rows never stored
    const half8* ap = (const half8*)(yin + (size_t)arow * DIM + q * 8);
    half8 a0 = ap[0], a1 = ap[4], a2 = ap[8], a3 = ap[12];   // k += 32 per step
    floatx4 acc[8];
#pragma unroll
    for (int n = 0; n < 8; ++n) acc[n] = (floatx4){0.f, 0.f, 0.f, 0.f};
#pragma unroll
    for (int n = 0; n < 8; ++n)
        acc[n] = __builtin_amdgcn_mfma_f32_16x16x32_f16(a0, Wf[(0 * 8 + n) * 64 + lane], acc[n], 0, 0, 0);
#pragma unroll
    for (int n = 0; n < 8; ++n)
        acc[n] = __builtin_amdgcn_mfma_f32_16x16x32_f16(a1, Wf[(1 * 8 + n) * 64 + lane], acc[n], 0, 0, 0);
#pragma unroll
    for (int n = 0; n < 8; ++n)
        acc[n] = __builtin_amdgcn_mfma_f32_16x16x32_f16(a2, Wf[(2 * 8 + n) * 64 + lane], acc[n], 0, 0, 0);
#pragma unroll
    for (int n = 0; n < 8; ++n)
        acc[n] = __builtin_amdgcn_mfma_f32_16x16x32_f16(a3, Wf[(3 * 8 + n) * 64 + lane], acc[n], 0, 0, 0);
#pragma unroll
    for (int n = 0; n < 8; ++n) {
#pragma unroll
        for (int r = 0; r < 4; ++r) {
            int row = r0 + q * 4 + r;
            if (row < NN)
                hout[(size_t)row * DIM + n * 16 + m] = (_Float16)acc[n][r];
        }
    }
}

// ---------------- fused conv: agg(fp16 gather) + self + bias + L2norm + ReLU (+pool) ----
__launch_bounds__(256, 8)
__global__ void conv_kernel(const half2v* __restrict__ h2, const float* __restrict__ bias,
                            const int* __restrict__ rowp, const unsigned* __restrict__ edges,
                            const float* __restrict__ selfn, half2v* __restrict__ out,
                            const int* __restrict__ batch, float* __restrict__ pooled,
                            int do_pool) {
    int wid = threadIdx.x >> 6;
    int lane = threadIdx.x & 63;
    int node = blockIdx.x * 4 + wid;
    if (node >= NN) return;
    int beg = rowp[node], end = rowp[node + 1];
    float ax = 0.f, ay = 0.f;
    int e = beg;
    for (; e + 4 <= end; e += 4) {
        unsigned r0 = __builtin_nontemporal_load(edges + e);
        unsigned r1 = __builtin_nontemporal_load(edges + e + 1);
        unsigned r2 = __builtin_nontemporal_load(edges + e + 2);
        unsigned r3 = __builtin_nontemporal_load(edges + e + 3);
        half2v v0 = h2[(size_t)(r0 & 0xFFFFu) * 64 + lane];
        half2v v1 = h2[(size_t)(r1 & 0xFFFFu) * 64 + lane];
        half2v v2 = h2[(size_t)(r2 & 0xFFFFu) * 64 + lane];
        half2v v3 = h2[(size_t)(r3 & 0xFFFFu) * 64 + lane];
        float w0 = hbits2f(r0 >> 16), w1 = hbits2f(r1 >> 16);
        float w2 = hbits2f(r2 >> 16), w3 = hbits2f(r3 >> 16);
        ax += w0 * (float)v0.x + w1 * (float)v1.x + w2 * (float)v2.x + w3 * (float)v3.x;
        ay += w0 * (float)v0.y + w1 * (float)v1.y + w2 * (float)v2.y + w3 * (float)v3.y;
    }
    for (; e < end; ++e) {
        unsigned r = __builtin_nontemporal_load(edges + e);
        half2v v = h2[(size_t)(r & 0xFFFFu) * 64 + lane];
        float w = hbits2f(r >> 16);
        ax += w * (float)v.x;
        ay += w * (float)v.y;
    }
    float sn = selfn[node];
    half2v hv = h2[(size_t)node * 64 + lane];
    ax += sn * (float)hv.x + bias[2 * lane];
    ay += sn * (float)hv.y + bias[2 * lane + 1];
    float ss = ax * ax + ay * ay;
#pragma unroll
    for (int off = 32; off; off >>= 1) ss += __shfl_xor(ss, off);
    float inv = 1.0f / fmaxf(sqrtf(ss), 1e-12f);
    float ox = fmaxf(ax * inv, 0.f);
    float oy = fmaxf(ay * inv, 0.f);
    if (!do_pool) {
        half2v o;
        o.x = (_Float16)ox;
        o.y = (_Float16)oy;
        out[(size_t)node * 64 + lane] = o;   // cached store: y stays L2-hot for GEMM
    } else {
        int g = batch[node];
        atomicAdd(&pooled[g * DIM + 2 * lane], ox);
        atomicAdd(&pooled[g * DIM + 2 * lane + 1], oy);
    }
}

// ---------------- head: z = relu(pooled@W1+b1); logits = z@W2+b2 ----------------
__launch_bounds__(128)
__global__ void head_kernel(const float* __restrict__ pooled, const float* __restrict__ w1,
                            const float* __restrict__ b1, const float* __restrict__ w2,
                            const float* __restrict__ b2, float* __restrict__ out) {
    __shared__ float sp[DIM];
    __shared__ float red[4];
    int g = blockIdx.x;
    int k = threadIdx.x;
    sp[k] = pooled[g * DIM + k];
    __syncthreads();
    float acc = b1[k];
#pragma unroll 8
    for (int j = 0; j < DIM; ++j) acc += sp[j] * w1[j * DIM + k];
    float z = fmaxf(acc, 0.f);
    float p0 = z * w2[k * 2 + 0];
    float p1 = z * w2[k * 2 + 1];
#pragma unroll
    for (int off = 32; off; off >>= 1) {
        p0 += __shfl_xor(p0, off);
        p1 += __shfl_xor(p1, off);
    }
    if ((k & 63) == 0) {
        red[(k >> 6) * 2 + 0] = p0;
        red[(k >> 6) * 2 + 1] = p1;
    }
    __syncthreads();
    if (k == 0) {
        out[g * 2 + 0] = red[0] + red[2] + b2[0];
        out[g * 2 + 1] = red[1] + red[3] + b2[1];
    }
}

extern "C" void kernel_launch(void* const* d_in, const int* in_sizes, int n_in,
                              void* d_out, int out_size, void* d_ws, size_t ws_size,
                              hipStream_t stream) {
    const float* x    = (const float*)d_in[0];
    const int* eidx   = (const int*)d_in[1];
    const int* batch  = (const int*)d_in[2];
    const float* W0   = (const float*)d_in[3];
    const float* b0   = (const float*)d_in[4];
    const float* W1   = (const float*)d_in[5];
    const float* b1   = (const float*)d_in[6];
    const float* W2   = (const float*)d_in[7];
    const float* b2   = (const float*)d_in[8];
    const float* l1w  = (const float*)d_in[9];
    const float* l1b  = (const float*)d_in[10];
    const float* l2w  = (const float*)d_in[11];
    const float* l2b  = (const float*)d_in[12];
    float* out = (float*)d_out;

    char* w = (char*)d_ws;
    float* disqrt = (float*)w; w += (size_t)NN * 4;
    float* selfn  = (float*)w; w += (size_t)NN * 4;
    int*   cnt    = (int*)w;   w += (size_t)NN * 4;
    int*   rowp   = (int*)w;   w += (size_t)(NN + 8) * 4;
    int*   cursor = (int*)w;   w += (size_t)NN * 4;
    int*   lexcl  = (int*)w;   w += (size_t)NN * 4;
    int*   bsum   = (int*)w;   w += 1024 * 4;
    int*   boffs  = (int*)w;   w += 1024 * 4;
    unsigned* edges = (unsigned*)w; w += (size_t)NE * 4;
    half8* wf     = (half8*)w; w += (size_t)3 * 2048 * 16;
    _Float16* xh  = (_Float16*)w; w += (size_t)NN * DIM * 2;
    _Float16* bufh = (_Float16*)w; w += (size_t)NN * DIM * 2;   // h (gemm out, gathered)
    _Float16* bufy = (_Float16*)w; w += (size_t)NN * DIM * 2;   // y (conv out)
    float* pooled = (float*)w; w += (size_t)NG * DIM * 4;

    const int* src = eidx;
    const int* dst = eidx + NE;

    init_kernel<<<256, 256, 0, stream>>>(cnt, pooled);
    count_kernel<<<(NE + 255) / 256, 256, 0, stream>>>(dst, cnt);
    scan1_kernel<<<NBLK, 1024, 0, stream>>>(cnt, lexcl, bsum, disqrt, selfn);
    scan2_kernel<<<1, 1024, 0, stream>>>(bsum, boffs, rowp);
    scan3_kernel<<<NBLK, 1024, 0, stream>>>(lexcl, boffs, rowp, cursor);
    for (int p = 0; p < NPASS; ++p)
        scatter_kernel<<<(NE + 255) / 256, 256, 0, stream>>>(src, dst, disqrt, cursor, edges,
                                                             p * PASSW, (p + 1) * PASSW);
    cvt_kernel<<<(NN * DIM / 4 + 255) / 256, 256, 0, stream>>>(x, xh);
    cvtw_kernel<<<3, 256, 0, stream>>>(W0, W1, W2, wf);

    const int CG = (NN + 3) / 4;        // 12500 blocks, one wave per node
    const int GG = (NN + 63) / 64;      // 782 blocks, one 64-row group per block

    gemm_mfma<<<GG, 256, 0, stream>>>(xh, wf, bufh);
    conv_kernel<<<CG, 256, 0, stream>>>((const half2v*)bufh, b0, rowp, edges, selfn,
                                        (half2v*)bufy, batch, pooled, 0);
    gemm_mfma<<<GG, 256, 0, stream>>>(bufy, wf + 2048, bufh);
    conv_kernel<<<CG, 256, 0, stream>>>((const half2v*)bufh, b1, rowp, edges, selfn,
                                        (half2v*)bufy, batch, pooled, 0);
    gemm_mfma<<<GG, 256, 0, stream>>>(bufy, wf + 4096, bufh);
    conv_kernel<<<CG, 256, 0, stream>>>((const half2v*)bufh, b2, rowp, edges, selfn,
                                        (half2v*)bufy, batch, pooled, 1);
    head_kernel<<<NG, 128, 0, stream>>>(pooled, l1w, l1b, l2w, l2b, out);
}

// Round 9
// 577.177 us; speedup vs baseline: 5.8058x; 1.0101x over previous
//
#include <hip/hip_runtime.h>

#define NN 50000
#define NE 1600000
#define DIM 128
#define NG  512
#define NBLK 49        // ceil(NN/1024)

typedef float    vfloat4 __attribute__((ext_vector_type(4)));
typedef float    floatx4 __attribute__((ext_vector_type(4)));
typedef unsigned vuint4  __attribute__((ext_vector_type(4)));
typedef _Float16 half2v  __attribute__((ext_vector_type(2)));
typedef _Float16 half4v  __attribute__((ext_vector_type(4)));
typedef _Float16 half8   __attribute__((ext_vector_type(8)));

__device__ __forceinline__ float hbits2f(unsigned u) {
    union { unsigned short us; _Float16 h; } c;
    c.us = (unsigned short)u;
    return (float)c.h;
}

// ---------------- init: zero cnt + pooled ----------------
__global__ void init_kernel(int* __restrict__ cnt, float* __restrict__ pooled) {
    int i = blockIdx.x * blockDim.x + threadIdx.x;
    int stride = gridDim.x * blockDim.x;
    for (int j = i; j < NN; j += stride) cnt[j] = 0;
    for (int j = i; j < NG * DIM; j += stride) pooled[j] = 0.f;
}

// ---------------- in-degree count (by dst) ----------------
__global__ void count_kernel(const int* __restrict__ dst, int* __restrict__ cnt) {
    int e = blockIdx.x * blockDim.x + threadIdx.x;
    if (e < NE) atomicAdd(&cnt[dst[e]], 1);
}

// ---------------- scan phase 1: per-block local scan + coeffs ----------------
__global__ void scan1_kernel(const int* __restrict__ cnt, int* __restrict__ lexcl,
                             int* __restrict__ bsum, float* __restrict__ disqrt,
                             float* __restrict__ selfn) {
    __shared__ int sd[1024];
    int t = threadIdx.x;
    int i = blockIdx.x * 1024 + t;
    int v = (i < NN) ? cnt[i] : 0;
    sd[t] = v;
    __syncthreads();
    for (int off = 1; off < 1024; off <<= 1) {
        int add = (t >= off) ? sd[t - off] : 0;
        __syncthreads();
        sd[t] += add;
        __syncthreads();
    }
    int incl = sd[t];
    if (i < NN) {
        lexcl[i] = incl - v;
        float dg = (float)(v + 1);
        disqrt[i] = 1.0f / sqrtf(dg);
        selfn[i] = 1.0f / dg;
    }
    if (t == 1023) bsum[blockIdx.x] = incl;
}

// ---------------- scan phase 2+3 merged: block offset via wave-reduce, write rowp ----
__global__ void scan23_kernel(const int* __restrict__ lexcl, const int* __restrict__ bsum,
                              int* __restrict__ rowp, int* __restrict__ cursor) {
    __shared__ int s_off;
    int t = threadIdx.x;
    if (t < 64) {
        int v = (t < NBLK) ? bsum[t] : 0;
        int pre = (t < (int)blockIdx.x) ? v : 0;
        int all = v;
#pragma unroll
        for (int off = 32; off; off >>= 1) {
            pre += __shfl_xor(pre, off);
            all += __shfl_xor(all, off);
        }
        if (t == 0) {
            s_off = pre;
            if (blockIdx.x == 0) rowp[NN] = all;   // grand total (== NE)
        }
    }
    __syncthreads();
    int i = blockIdx.x * 1024 + t;
    if (i < NN) {
        int v = lexcl[i] + s_off;
        rowp[i] = v;
        cursor[i] = v;
    }
}

// ---------------- scatter: single pass, CACHED stores (lines coalesce in L2) ----------
__global__ void scatter_kernel(const int* __restrict__ src, const int* __restrict__ dst,
                               const float* __restrict__ disqrt, int* __restrict__ cursor,
                               unsigned* __restrict__ edges) {
    int e = blockIdx.x * blockDim.x + threadIdx.x;
    if (e >= NE) return;
    int d = dst[e];
    int s = src[e];
    float en = disqrt[s] * disqrt[d];
    union { _Float16 h; unsigned short us; } c;
    c.h = (_Float16)en;
    unsigned rec = (unsigned)s | ((unsigned)c.us << 16);   // NN < 65536
    int pos = atomicAdd(&cursor[d], 1);
    edges[pos] = rec;
}

// ---------------- fused convert: W0/W1/W2 -> B-frag layout, x -> fp16 ----------------
__global__ void cvtxw_kernel(const float* __restrict__ x, _Float16* __restrict__ xh,
                             const float* __restrict__ W0, const float* __restrict__ W1,
                             const float* __restrict__ W2, half8* __restrict__ wf) {
    if (blockIdx.x < 3) {
        const float* Ws[3] = {W0, W1, W2};
        const float* W = Ws[blockIdx.x];
        half8* outp = wf + (size_t)blockIdx.x * 2048;
        for (int idx = threadIdx.x; idx < 2048; idx += 256) {
            int t = idx >> 9;
            int n = (idx >> 6) & 7;
            int ln = idx & 63;
            int q = ln >> 4, c = ln & 15;
            const float* wp = W + (t * 32 + q * 8) * DIM + n * 16 + c;
            half8 f;
#pragma unroll
            for (int j = 0; j < 8; ++j) f[j] = (_Float16)wp[j * DIM];
            outp[idx] = f;
        }
    } else {
        int i = (blockIdx.x - 3) * 256 + threadIdx.x;   // one float4 per thread
        if (i < NN * DIM / 4) {
            vfloat4 v = ((const vfloat4*)x)[i];
            half4v o;
            o.x = (_Float16)v.x; o.y = (_Float16)v.y;
            o.z = (_Float16)v.z; o.w = (_Float16)v.w;
            ((half4v*)xh)[i] = o;
        }
    }
}

// ---------------- GEMM via MFMA: one 64-row group per block ----------------
__launch_bounds__(256, 2)
__global__ void gemm_mfma(const _Float16* __restrict__ yin, const half8* __restrict__ wfl,
                          _Float16* __restrict__ hout) {
    __shared__ half8 Wf[2048];   // 32 KB
    int tid = threadIdx.x;
    for (int idx = tid; idx < 2048; idx += 256) Wf[idx] = wfl[idx];
    __syncthreads();
    int wid = tid >> 6, lane = tid & 63;
    int q = lane >> 4, m = lane & 15;
    int r0 = blockIdx.x * 64 + wid * 16;
    int arow = r0 + m;
    if (arow > NN - 1) arow = NN - 1;      // clamp; clamped rows never stored
    const half8* ap = (const half8*)(yin + (size_t)arow * DIM + q * 8);
    half8 a0 = ap[0], a1 = ap[4], a2 = ap[8], a3 = ap[12];   // k += 32 per step
    floatx4 acc[8];
#pragma unroll
    for (int n = 0; n < 8; ++n) acc[n] = (floatx4){0.f, 0.f, 0.f, 0.f};
#pragma unroll
    for (int n = 0; n < 8; ++n)
        acc[n] = __builtin_amdgcn_mfma_f32_16x16x32_f16(a0, Wf[(0 * 8 + n) * 64 + lane], acc[n], 0, 0, 0);
#pragma unroll
    for (int n = 0; n < 8; ++n)
        acc[n] = __builtin_amdgcn_mfma_f32_16x16x32_f16(a1, Wf[(1 * 8 + n) * 64 + lane], acc[n], 0, 0, 0);
#pragma unroll
    for (int n = 0; n < 8; ++n)
        acc[n] = __builtin_amdgcn_mfma_f32_16x16x32_f16(a2, Wf[(2 * 8 + n) * 64 + lane], acc[n], 0, 0, 0);
#pragma unroll
    for (int n = 0; n < 8; ++n)
        acc[n] = __builtin_amdgcn_mfma_f32_16x16x32_f16(a3, Wf[(3 * 8 + n) * 64 + lane], acc[n], 0, 0, 0);
#pragma unroll
    for (int n = 0; n < 8; ++n) {
#pragma unroll
        for (int r = 0; r < 4; ++r) {
            int row = r0 + q * 4 + r;
            if (row < NN)
                hout[(size_t)row * DIM + n * 16 + m] = (_Float16)acc[n][r];
        }
    }
}

// ---------------- fused conv: agg(fp16 gather) + self + bias + L2norm + ReLU (+pool) ----
__launch_bounds__(256, 8)
__global__ void conv_kernel(const half2v* __restrict__ h2, const float* __restrict__ bias,
                            const int* __restrict__ rowp, const unsigned* __restrict__ edges,
                            const float* __restrict__ selfn, half2v* __restrict__ out,
                            const int* __restrict__ batch, float* __restrict__ pooled,
                            int do_pool) {
    int wid = threadIdx.x >> 6;
    int lane = threadIdx.x & 63;
    int node = blockIdx.x * 4 + wid;
    if (node >= NN) return;
    int beg = rowp[node], end = rowp[node + 1];
    float ax = 0.f, ay = 0.f;
    int e = beg;
    // head: scalar until 16B-aligned edge index
    for (; e < end && (e & 3); ++e) {
        unsigned r = __builtin_nontemporal_load(edges + e);
        half2v v = h2[(size_t)(r & 0xFFFFu) * 64 + lane];
        float w = hbits2f(r >> 16);
        ax += w * (float)v.x;
        ay += w * (float)v.y;
    }
    for (; e + 4 <= end; e += 4) {
        vuint4 rr = __builtin_nontemporal_load((const vuint4*)(edges + e));
        unsigned r0 = rr.x, r1 = rr.y, r2 = rr.z, r3 = rr.w;
        half2v v0 = h2[(size_t)(r0 & 0xFFFFu) * 64 + lane];
        half2v v1 = h2[(size_t)(r1 & 0xFFFFu) * 64 + lane];
        half2v v2 = h2[(size_t)(r2 & 0xFFFFu) * 64 + lane];
        half2v v3 = h2[(size_t)(r3 & 0xFFFFu) * 64 + lane];
        float w0 = hbits2f(r0 >> 16), w1 = hbits2f(r1 >> 16);
        float w2 = hbits2f(r2 >> 16), w3 = hbits2f(r3 >> 16);
        ax += w0 * (float)v0.x + w1 * (float)v1.x + w2 * (float)v2.x + w3 * (float)v3.x;
        ay += w0 * (float)v0.y + w1 * (float)v1.y + w2 * (float)v2.y + w3 * (float)v3.y;
    }
    for (; e < end; ++e) {
        unsigned r = __builtin_nontemporal_load(edges + e);
        half2v v = h2[(size_t)(r & 0xFFFFu) * 64 + lane];
        float w = hbits2f(r >> 16);
        ax += w * (float)v.x;
        ay += w * (float)v.y;
    }
    float sn = selfn[node];
    half2v hv = h2[(size_t)node * 64 + lane];
    ax += sn * (float)hv.x + bias[2 * lane];
    ay += sn * (float)hv.y + bias[2 * lane + 1];
    float ss = ax * ax + ay * ay;
#pragma unroll
    for (int off = 32; off; off >>= 1) ss += __shfl_xor(ss, off);
    float inv = 1.0f / fmaxf(sqrtf(ss), 1e-12f);
    float ox = fmaxf(ax * inv, 0.f);
    float oy = fmaxf(ay * inv, 0.f);
    if (!do_pool) {
        half2v o;
        o.x = (_Float16)ox;
        o.y = (_Float16)oy;
        out[(size_t)node * 64 + lane] = o;   // cached store: y stays L2-hot for GEMM
    } else {
        int g = batch[node];
        atomicAdd(&pooled[g * DIM + 2 * lane], ox);
        atomicAdd(&pooled[g * DIM + 2 * lane + 1], oy);
    }
}

// ---------------- head: z = relu(pooled@W1+b1); logits = z@W2+b2 ----------------
__launch_bounds__(128)
__global__ void head_kernel(const float* __restrict__ pooled, const float* __restrict__ w1,
                            const float* __restrict__ b1, const float* __restrict__ w2,
                            const float* __restrict__ b2, float* __restrict__ out) {
    __shared__ float sp[DIM];
    __shared__ float red[4];
    int g = blockIdx.x;
    int k = threadIdx.x;
    sp[k] = pooled[g * DIM + k];
    __syncthreads();
    float acc = b1[k];
#pragma unroll 8
    for (int j = 0; j < DIM; ++j) acc += sp[j] * w1[j * DIM + k];
    float z = fmaxf(acc, 0.f);
    float p0 = z * w2[k * 2 + 0];
    float p1 = z * w2[k * 2 + 1];
#pragma unroll
    for (int off = 32; off; off >>= 1) {
        p0 += __shfl_xor(p0, off);
        p1 += __shfl_xor(p1, off);
    }
    if ((k & 63) == 0) {
        red[(k >> 6) * 2 + 0] = p0;
        red[(k >> 6) * 2 + 1] = p1;
    }
    __syncthreads();
    if (k == 0) {
        out[g * 2 + 0] = red[0] + red[2] + b2[0];
        out[g * 2 + 1] = red[1] + red[3] + b2[1];
    }
}

extern "C" void kernel_launch(void* const* d_in, const int* in_sizes, int n_in,
                              void* d_out, int out_size, void* d_ws, size_t ws_size,
                              hipStream_t stream) {
    const float* x    = (const float*)d_in[0];
    const int* eidx   = (const int*)d_in[1];
    const int* batch  = (const int*)d_in[2];
    const float* W0   = (const float*)d_in[3];
    const float* b0   = (const float*)d_in[4];
    const float* W1   = (const float*)d_in[5];
    const float* b1   = (const float*)d_in[6];
    const float* W2   = (const float*)d_in[7];
    const float* b2   = (const float*)d_in[8];
    const float* l1w  = (const float*)d_in[9];
    const float* l1b  = (const float*)d_in[10];
    const float* l2w  = (const float*)d_in[11];
    const float* l2b  = (const float*)d_in[12];
    float* out = (float*)d_out;

    char* w = (char*)d_ws;
    float* disqrt = (float*)w; w += (size_t)NN * 4;
    float* selfn  = (float*)w; w += (size_t)NN * 4;
    int*   cnt    = (int*)w;   w += (size_t)NN * 4;
    int*   rowp   = (int*)w;   w += (size_t)(NN + 8) * 4;
    int*   cursor = (int*)w;   w += (size_t)NN * 4;
    int*   lexcl  = (int*)w;   w += (size_t)NN * 4;
    int*   bsum   = (int*)w;   w += 1024 * 4;
    unsigned* edges = (unsigned*)w; w += (size_t)NE * 4;
    half8* wf     = (half8*)w; w += (size_t)3 * 2048 * 16;
    _Float16* xh  = (_Float16*)w; w += (size_t)NN * DIM * 2;
    _Float16* bufh = (_Float16*)w; w += (size_t)NN * DIM * 2;   // h (gemm out, gathered)
    _Float16* bufy = (_Float16*)w; w += (size_t)NN * DIM * 2;   // y (conv out)
    float* pooled = (float*)w; w += (size_t)NG * DIM * 4;

    const int* src = eidx;
    const int* dst = eidx + NE;

    init_kernel<<<256, 256, 0, stream>>>(cnt, pooled);
    count_kernel<<<(NE + 255) / 256, 256, 0, stream>>>(dst, cnt);
    scan1_kernel<<<NBLK, 1024, 0, stream>>>(cnt, lexcl, bsum, disqrt, selfn);
    scan23_kernel<<<NBLK, 1024, 0, stream>>>(lexcl, bsum, rowp, cursor);
    scatter_kernel<<<(NE + 255) / 256, 256, 0, stream>>>(src, dst, disqrt, cursor, edges);
    cvtxw_kernel<<<3 + (NN * DIM / 4 + 255) / 256, 256, 0, stream>>>(x, xh, W0, W1, W2, wf);

    const int CG = (NN + 3) / 4;        // 12500 blocks, one wave per node
    const int GG = (NN + 63) / 64;      // 782 blocks, one 64-row group per block

    gemm_mfma<<<GG, 256, 0, stream>>>(xh, wf, bufh);
    conv_kernel<<<CG, 256, 0, stream>>>((const half2v*)bufh, b0, rowp, edges, selfn,
                                        (half2v*)bufy, batch, pooled, 0);
    gemm_mfma<<<GG, 256, 0, stream>>>(bufy, wf + 2048, bufh);
    conv_kernel<<<CG, 256, 0, stream>>>((const half2v*)bufh, b1, rowp, edges, selfn,
                                        (half2v*)bufy, batch, pooled, 0);
    gemm_mfma<<<GG, 256, 0, stream>>>(bufy, wf + 4096, bufh);
    conv_kernel<<<CG, 256, 0, stream>>>((const half2v*)bufh, b2, rowp, edges, selfn,
                                        (half2v*)bufy, batch, pooled, 1);
    head_kernel<<<NG, 128, 0, stream>>>(pooled, l1w, l1b, l2w, l2b, out);
}

// Round 10
// 487.414 us; speedup vs baseline: 6.8750x; 1.1842x over previous
//
#include <hip/hip_runtime.h>

#define NN 50000
#define NE 1600000
#define DIM 128
#define NG  512
#define MAXD 192     // bucket capacity; Poisson(λ=32) P(deg>192) ~ e-120, deterministic inputs

typedef float    vfloat4 __attribute__((ext_vector_type(4)));
typedef float    floatx4 __attribute__((ext_vector_type(4)));
typedef unsigned vuint4  __attribute__((ext_vector_type(4)));
typedef _Float16 half2v  __attribute__((ext_vector_type(2)));
typedef _Float16 half4v  __attribute__((ext_vector_type(4)));
typedef _Float16 half8   __attribute__((ext_vector_type(8)));

// ---------------- fused init: W->frag cvt | x->fp16 | zero cursor+pooled ----------------
__global__ void initcvt_kernel(const float* __restrict__ x, _Float16* __restrict__ xh,
                               const float* __restrict__ W0, const float* __restrict__ W1,
                               const float* __restrict__ W2, half8* __restrict__ wf,
                               int* __restrict__ cursor, float* __restrict__ pooled) {
    int b = blockIdx.x;
    if (b < 3) {
        const float* Ws[3] = {W0, W1, W2};
        const float* W = Ws[b];
        half8* outp = wf + (size_t)b * 2048;
        for (int idx = threadIdx.x; idx < 2048; idx += 256) {
            int t = idx >> 9;
            int n = (idx >> 6) & 7;
            int ln = idx & 63;
            int q = ln >> 4, c = ln & 15;
            const float* wp = W + (t * 32 + q * 8) * DIM + n * 16 + c;
            half8 f;
#pragma unroll
            for (int j = 0; j < 8; ++j) f[j] = (_Float16)wp[j * DIM];
            outp[idx] = f;
        }
    } else if (b < 3 + 6250) {
        int i = (b - 3) * 256 + threadIdx.x;   // one float4 per thread, 1.6M total
        vfloat4 v = ((const vfloat4*)x)[i];
        half4v o;
        o.x = (_Float16)v.x; o.y = (_Float16)v.y;
        o.z = (_Float16)v.z; o.w = (_Float16)v.w;
        ((half4v*)xh)[i] = o;
    } else {
        int k = (b - 6253) * 256 + threadIdx.x;
        if (k < NN) cursor[k] = 0;
        else if (k < NN + NG * DIM) pooled[k - NN] = 0.f;
    }
}

// ---------------- scatter into fixed buckets: cursor doubles as degree counter --------
__global__ void scatter_kernel(const int* __restrict__ src, const int* __restrict__ dst,
                               int* __restrict__ cursor, unsigned short* __restrict__ edges) {
    int e = blockIdx.x * blockDim.x + threadIdx.x;
    if (e >= NE) return;
    int d = dst[e];
    int s = src[e];
    int pos = atomicAdd(&cursor[d], 1);
    edges[(size_t)d * MAXD + pos] = (unsigned short)s;   // NN < 65536; cached store
}

// ---------------- coeffs from bucket counts ----------------
__global__ void coeff_kernel(const int* __restrict__ cnt, float* __restrict__ dq,
                             float* __restrict__ selfn) {
    int i = blockIdx.x * 256 + threadIdx.x;
    if (i >= NN) return;
    float dg = (float)(cnt[i] + 1);
    dq[i] = 1.0f / sqrtf(dg);
    selfn[i] = 1.0f / dg;
}

// ---------------- GEMM via MFMA: one 64-row group per block ----------------
__launch_bounds__(256, 2)
__global__ void gemm_mfma(const _Float16* __restrict__ yin, const half8* __restrict__ wfl,
                          _Float16* __restrict__ hout) {
    __shared__ half8 Wf[2048];   // 32 KB
    int tid = threadIdx.x;
    for (int idx = tid; idx < 2048; idx += 256) Wf[idx] = wfl[idx];
    __syncthreads();
    int wid = tid >> 6, lane = tid & 63;
    int q = lane >> 4, m = lane & 15;
    int r0 = blockIdx.x * 64 + wid * 16;
    int arow = r0 + m;
    if (arow > NN - 1) arow = NN - 1;      // clamp; clamped rows never stored
    const half8* ap = (const half8*)(yin + (size_t)arow * DIM + q * 8);
    half8 a0 = ap[0], a1 = ap[4], a2 = ap[8], a3 = ap[12];   // k += 32 per step
    floatx4 acc[8];
#pragma unroll
    for (int n = 0; n < 8; ++n) acc[n] = (floatx4){0.f, 0.f, 0.f, 0.f};
#pragma unroll
    for (int n = 0; n < 8; ++n)
        acc[n] = __builtin_amdgcn_mfma_f32_16x16x32_f16(a0, Wf[(0 * 8 + n) * 64 + lane], acc[n], 0, 0, 0);
#pragma unroll
    for (int n = 0; n < 8; ++n)
        acc[n] = __builtin_amdgcn_mfma_f32_16x16x32_f16(a1, Wf[(1 * 8 + n) * 64 + lane], acc[n], 0, 0, 0);
#pragma unroll
    for (int n = 0; n < 8; ++n)
        acc[n] = __builtin_amdgcn_mfma_f32_16x16x32_f16(a2, Wf[(2 * 8 + n) * 64 + lane], acc[n], 0, 0, 0);
#pragma unroll
    for (int n = 0; n < 8; ++n)
        acc[n] = __builtin_amdgcn_mfma_f32_16x16x32_f16(a3, Wf[(3 * 8 + n) * 64 + lane], acc[n], 0, 0, 0);
#pragma unroll
    for (int n = 0; n < 8; ++n) {
#pragma unroll
        for (int r = 0; r < 4; ++r) {
            int row = r0 + q * 4 + r;
            if (row < NN)
                hout[(size_t)row * DIM + n * 16 + m] = (_Float16)acc[n][r];
        }
    }
}

// ---------------- fused conv: gather + on-the-fly norm + self + bias + L2norm/ReLU ----
// y[d] = dq[d] * Sum_e dq[s_e] h[s_e]  +  selfn[d] h[d]  +  b ; then L2-normalize+ReLU.
__launch_bounds__(256, 8)
__global__ void conv_kernel(const half2v* __restrict__ h2, const float* __restrict__ bias,
                            const int* __restrict__ cnt, const unsigned short* __restrict__ edges,
                            const float* __restrict__ dq, const float* __restrict__ selfn,
                            half2v* __restrict__ out, const int* __restrict__ batch,
                            float* __restrict__ pooled, int do_pool) {
    int wid = threadIdx.x >> 6;
    int lane = threadIdx.x & 63;
    int node = blockIdx.x * 4 + wid;
    if (node >= NN) return;
    int deg = cnt[node];
    const unsigned short* ep = edges + (size_t)node * MAXD;   // 16B-aligned (384B rows)
    float ax = 0.f, ay = 0.f;
    int e = 0;
    for (; e + 8 <= deg; e += 8) {
        vuint4 pk = __builtin_nontemporal_load((const vuint4*)(ep + e));
        unsigned s0 = pk.x & 0xFFFFu, s1 = pk.x >> 16;
        unsigned s2 = pk.y & 0xFFFFu, s3 = pk.y >> 16;
        unsigned s4 = pk.z & 0xFFFFu, s5 = pk.z >> 16;
        unsigned s6 = pk.w & 0xFFFFu, s7 = pk.w >> 16;
        float d0 = dq[s0], d1 = dq[s1], d2 = dq[s2], d3 = dq[s3];
        float d4 = dq[s4], d5 = dq[s5], d6 = dq[s6], d7 = dq[s7];
        half2v v0 = h2[(size_t)s0 * 64 + lane];
        half2v v1 = h2[(size_t)s1 * 64 + lane];
        half2v v2 = h2[(size_t)s2 * 64 + lane];
        half2v v3 = h2[(size_t)s3 * 64 + lane];
        half2v v4 = h2[(size_t)s4 * 64 + lane];
        half2v v5 = h2[(size_t)s5 * 64 + lane];
        half2v v6 = h2[(size_t)s6 * 64 + lane];
        half2v v7 = h2[(size_t)s7 * 64 + lane];
        ax += d0 * (float)v0.x + d1 * (float)v1.x + d2 * (float)v2.x + d3 * (float)v3.x
            + d4 * (float)v4.x + d5 * (float)v5.x + d6 * (float)v6.x + d7 * (float)v7.x;
        ay += d0 * (float)v0.y + d1 * (float)v1.y + d2 * (float)v2.y + d3 * (float)v3.y
            + d4 * (float)v4.y + d5 * (float)v5.y + d6 * (float)v6.y + d7 * (float)v7.y;
    }
    for (; e < deg; ++e) {
        unsigned s = ep[e];
        float ds = dq[s];
        half2v v = h2[(size_t)s * 64 + lane];
        ax += ds * (float)v.x;
        ay += ds * (float)v.y;
    }
    float dqd = dq[node];
    float sn = selfn[node];
    half2v hv = h2[(size_t)node * 64 + lane];
    ax = ax * dqd + sn * (float)hv.x + bias[2 * lane];
    ay = ay * dqd + sn * (float)hv.y + bias[2 * lane + 1];
    float ss = ax * ax + ay * ay;
#pragma unroll
    for (int off = 32; off; off >>= 1) ss += __shfl_xor(ss, off);
    float inv = 1.0f / fmaxf(sqrtf(ss), 1e-12f);
    float ox = fmaxf(ax * inv, 0.f);
    float oy = fmaxf(ay * inv, 0.f);
    if (!do_pool) {
        half2v o;
        o.x = (_Float16)ox;
        o.y = (_Float16)oy;
        out[(size_t)node * 64 + lane] = o;   // cached store: y stays L2-hot for GEMM
    } else {
        int g = batch[node];
        atomicAdd(&pooled[g * DIM + 2 * lane], ox);
        atomicAdd(&pooled[g * DIM + 2 * lane + 1], oy);
    }
}

// ---------------- head: z = relu(pooled@W1+b1); logits = z@W2+b2 ----------------
__launch_bounds__(128)
__global__ void head_kernel(const float* __restrict__ pooled, const float* __restrict__ w1,
                            const float* __restrict__ b1, const float* __restrict__ w2,
                            const float* __restrict__ b2, float* __restrict__ out) {
    __shared__ float sp[DIM];
    __shared__ float red[4];
    int g = blockIdx.x;
    int k = threadIdx.x;
    sp[k] = pooled[g * DIM + k];
    __syncthreads();
    float acc = b1[k];
#pragma unroll 8
    for (int j = 0; j < DIM; ++j) acc += sp[j] * w1[j * DIM + k];
    float z = fmaxf(acc, 0.f);
    float p0 = z * w2[k * 2 + 0];
    float p1 = z * w2[k * 2 + 1];
#pragma unroll
    for (int off = 32; off; off >>= 1) {
        p0 += __shfl_xor(p0, off);
        p1 += __shfl_xor(p1, off);
    }
    if ((k & 63) == 0) {
        red[(k >> 6) * 2 + 0] = p0;
        red[(k >> 6) * 2 + 1] = p1;
    }
    __syncthreads();
    if (k == 0) {
        out[g * 2 + 0] = red[0] + red[2] + b2[0];
        out[g * 2 + 1] = red[1] + red[3] + b2[1];
    }
}

extern "C" void kernel_launch(void* const* d_in, const int* in_sizes, int n_in,
                              void* d_out, int out_size, void* d_ws, size_t ws_size,
                              hipStream_t stream) {
    const float* x    = (const float*)d_in[0];
    const int* eidx   = (const int*)d_in[1];
    const int* batch  = (const int*)d_in[2];
    const float* W0   = (const float*)d_in[3];
    const float* b0   = (const float*)d_in[4];
    const float* W1   = (const float*)d_in[5];
    const float* b1   = (const float*)d_in[6];
    const float* W2   = (const float*)d_in[7];
    const float* b2   = (const float*)d_in[8];
    const float* l1w  = (const float*)d_in[9];
    const float* l1b  = (const float*)d_in[10];
    const float* l2w  = (const float*)d_in[11];
    const float* l2b  = (const float*)d_in[12];
    float* out = (float*)d_out;

    char* w = (char*)d_ws;
    float* dq     = (float*)w; w += (size_t)NN * 4;
    float* selfn  = (float*)w; w += (size_t)NN * 4;
    int*   cursor = (int*)w;   w += (size_t)NN * 4;
    unsigned short* edges = (unsigned short*)w; w += (size_t)NN * MAXD * 2;  // 19.2 MB
    half8* wf     = (half8*)w; w += (size_t)3 * 2048 * 16;
    _Float16* xh  = (_Float16*)w; w += (size_t)NN * DIM * 2;
    _Float16* bufh = (_Float16*)w; w += (size_t)NN * DIM * 2;   // h (gemm out, gathered)
    _Float16* bufy = (_Float16*)w; w += (size_t)NN * DIM * 2;   // y (conv out)
    float* pooled = (float*)w; w += (size_t)NG * DIM * 4;

    const int* src = eidx;
    const int* dst = eidx + NE;

    initcvt_kernel<<<6705, 256, 0, stream>>>(x, xh, W0, W1, W2, wf, cursor, pooled);
    scatter_kernel<<<(NE + 255) / 256, 256, 0, stream>>>(src, dst, cursor, edges);
    coeff_kernel<<<(NN + 255) / 256, 256, 0, stream>>>(cursor, dq, selfn);

    const int CG = (NN + 3) / 4;        // 12500 blocks, one wave per node
    const int GG = (NN + 63) / 64;      // 782 blocks, one 64-row group per block

    gemm_mfma<<<GG, 256, 0, stream>>>(xh, wf, bufh);
    conv_kernel<<<CG, 256, 0, stream>>>((const half2v*)bufh, b0, cursor, edges, dq, selfn,
                                        (half2v*)bufy, batch, pooled, 0);
    gemm_mfma<<<GG, 256, 0, stream>>>(bufy, wf + 2048, bufh);
    conv_kernel<<<CG, 256, 0, stream>>>((const half2v*)bufh, b1, cursor, edges, dq, selfn,
                                        (half2v*)bufy, batch, pooled, 0);
    gemm_mfma<<<GG, 256, 0, stream>>>(bufy, wf + 4096, bufh);
    conv_kernel<<<CG, 256, 0, stream>>>((const half2v*)bufh, b2, cursor, edges, dq, selfn,
                                        (half2v*)bufy, batch, pooled, 1);
    head_kernel<<<NG, 128, 0, stream>>>(pooled, l1w, l1b, l2w, l2b, out);
}

// Round 11
// 471.063 us; speedup vs baseline: 7.1137x; 1.0347x over previous
//
#include <hip/hip_runtime.h>

#define NN 50000
#define NE 1600000
#define DIM 128
#define NG  512
#define MAXD 192     // bucket capacity; Poisson(lambda=32), P(any deg>192) astronomically small
#define NPASS 4
#define PASSW 12500  // NN / NPASS

typedef float    vfloat4 __attribute__((ext_vector_type(4)));
typedef float    floatx4 __attribute__((ext_vector_type(4)));
typedef unsigned vuint4  __attribute__((ext_vector_type(4)));
typedef _Float16 half2v  __attribute__((ext_vector_type(2)));
typedef _Float16 half8   __attribute__((ext_vector_type(8)));

__device__ __forceinline__ half8 cvt8(vfloat4 a, vfloat4 b) {
    half8 r;
    r[0] = (_Float16)a.x; r[1] = (_Float16)a.y; r[2] = (_Float16)a.z; r[3] = (_Float16)a.w;
    r[4] = (_Float16)b.x; r[5] = (_Float16)b.y; r[6] = (_Float16)b.z; r[7] = (_Float16)b.w;
    return r;
}

// ---------------- fused init: W->frag cvt | zero cursor+pooled ----------------
__global__ void initcvt_kernel(const float* __restrict__ W0, const float* __restrict__ W1,
                               const float* __restrict__ W2, half8* __restrict__ wf,
                               int* __restrict__ cursor, float* __restrict__ pooled) {
    int b = blockIdx.x;
    if (b < 3) {
        const float* Ws[3] = {W0, W1, W2};
        const float* W = Ws[b];
        half8* outp = wf + (size_t)b * 2048;
        for (int idx = threadIdx.x; idx < 2048; idx += 256) {
            int t = idx >> 9;
            int n = (idx >> 6) & 7;
            int ln = idx & 63;
            int q = ln >> 4, c = ln & 15;
            const float* wp = W + (t * 32 + q * 8) * DIM + n * 16 + c;
            half8 f;
#pragma unroll
            for (int j = 0; j < 8; ++j) f[j] = (_Float16)wp[j * DIM];
            outp[idx] = f;
        }
    } else {
        int k = (b - 3) * 256 + threadIdx.x;
        if (k < NN) cursor[k] = 0;
        else if (k < NN + NG * DIM) pooled[k - NN] = 0.f;
    }
}

// ---------------- scatter pass: only dst in [lo,hi) -> 4.8 MB write region --------
// NT reads (streaming, keep L2 for the write lines); cached 2B stores coalesce in
// the small region. Cursor counts stay exact (ranges disjoint).
__global__ void scatter_kernel(const int* __restrict__ src, const int* __restrict__ dst,
                               int* __restrict__ cursor, unsigned short* __restrict__ edges,
                               int lo, int hi) {
    int e = blockIdx.x * blockDim.x + threadIdx.x;
    if (e >= NE) return;
    int d = __builtin_nontemporal_load(dst + e);
    if (d < lo || d >= hi) return;
    int s = __builtin_nontemporal_load(src + e);
    int pos = atomicAdd(&cursor[d], 1);
    edges[(size_t)d * MAXD + pos] = (unsigned short)s;   // NN < 65536
}

// ---------------- coeffs from bucket counts ----------------
__global__ void coeff_kernel(const int* __restrict__ cnt, float* __restrict__ dq,
                             float* __restrict__ selfn) {
    int i = blockIdx.x * 256 + threadIdx.x;
    if (i >= NN) return;
    float dg = (float)(cnt[i] + 1);
    dq[i] = 1.0f / sqrtf(dg);
    selfn[i] = 1.0f / dg;
}

// ---------------- layer-0 GEMM: reads fp32 x directly, converts in-register ----------
__launch_bounds__(256, 2)
__global__ void gemm0_mfma(const float* __restrict__ x, const half8* __restrict__ wfl,
                           _Float16* __restrict__ hout) {
    __shared__ half8 Wf[2048];   // 32 KB
    int tid = threadIdx.x;
    for (int idx = tid; idx < 2048; idx += 256) Wf[idx] = wfl[idx];
    __syncthreads();
    int wid = tid >> 6, lane = tid & 63;
    int q = lane >> 4, m = lane & 15;
    int r0 = blockIdx.x * 64 + wid * 16;
    int arow = r0 + m;
    if (arow > NN - 1) arow = NN - 1;
    const vfloat4* ap = (const vfloat4*)(x + (size_t)arow * DIM + q * 8);
    half8 a0 = cvt8(ap[0],  ap[1]);     // k-step stride = 32 floats = 8 vfloat4
    half8 a1 = cvt8(ap[8],  ap[9]);
    half8 a2 = cvt8(ap[16], ap[17]);
    half8 a3 = cvt8(ap[24], ap[25]);
    floatx4 acc[8];
#pragma unroll
    for (int n = 0; n < 8; ++n) acc[n] = (floatx4){0.f, 0.f, 0.f, 0.f};
#pragma unroll
    for (int n = 0; n < 8; ++n)
        acc[n] = __builtin_amdgcn_mfma_f32_16x16x32_f16(a0, Wf[(0 * 8 + n) * 64 + lane], acc[n], 0, 0, 0);
#pragma unroll
    for (int n = 0; n < 8; ++n)
        acc[n] = __builtin_amdgcn_mfma_f32_16x16x32_f16(a1, Wf[(1 * 8 + n) * 64 + lane], acc[n], 0, 0, 0);
#pragma unroll
    for (int n = 0; n < 8; ++n)
        acc[n] = __builtin_amdgcn_mfma_f32_16x16x32_f16(a2, Wf[(2 * 8 + n) * 64 + lane], acc[n], 0, 0, 0);
#pragma unroll
    for (int n = 0; n < 8; ++n)
        acc[n] = __builtin_amdgcn_mfma_f32_16x16x32_f16(a3, Wf[(3 * 8 + n) * 64 + lane], acc[n], 0, 0, 0);
#pragma unroll
    for (int n = 0; n < 8; ++n) {
#pragma unroll
        for (int r = 0; r < 4; ++r) {
            int row = r0 + q * 4 + r;
            if (row < NN)
                hout[(size_t)row * DIM + n * 16 + m] = (_Float16)acc[n][r];
        }
    }
}

// ---------------- GEMM via MFMA: one 64-row group per block (fp16 input) ----------------
__launch_bounds__(256, 2)
__global__ void gemm_mfma(const _Float16* __restrict__ yin, const half8* __restrict__ wfl,
                          _Float16* __restrict__ hout) {
    __shared__ half8 Wf[2048];   // 32 KB
    int tid = threadIdx.x;
    for (int idx = tid; idx < 2048; idx += 256) Wf[idx] = wfl[idx];
    __syncthreads();
    int wid = tid >> 6, lane = tid & 63;
    int q = lane >> 4, m = lane & 15;
    int r0 = blockIdx.x * 64 + wid * 16;
    int arow = r0 + m;
    if (arow > NN - 1) arow = NN - 1;
    const half8* ap = (const half8*)(yin + (size_t)arow * DIM + q * 8);
    half8 a0 = ap[0], a1 = ap[4], a2 = ap[8], a3 = ap[12];
    floatx4 acc[8];
#pragma unroll
    for (int n = 0; n < 8; ++n) acc[n] = (floatx4){0.f, 0.f, 0.f, 0.f};
#pragma unroll
    for (int n = 0; n < 8; ++n)
        acc[n] = __builtin_amdgcn_mfma_f32_16x16x32_f16(a0, Wf[(0 * 8 + n) * 64 + lane], acc[n], 0, 0, 0);
#pragma unroll
    for (int n = 0; n < 8; ++n)
        acc[n] = __builtin_amdgcn_mfma_f32_16x16x32_f16(a1, Wf[(1 * 8 + n) * 64 + lane], acc[n], 0, 0, 0);
#pragma unroll
    for (int n = 0; n < 8; ++n)
        acc[n] = __builtin_amdgcn_mfma_f32_16x16x32_f16(a2, Wf[(2 * 8 + n) * 64 + lane], acc[n], 0, 0, 0);
#pragma unroll
    for (int n = 0; n < 8; ++n)
        acc[n] = __builtin_amdgcn_mfma_f32_16x16x32_f16(a3, Wf[(3 * 8 + n) * 64 + lane], acc[n], 0, 0, 0);
#pragma unroll
    for (int n = 0; n < 8; ++n) {
#pragma unroll
        for (int r = 0; r < 4; ++r) {
            int row = r0 + q * 4 + r;
            if (row < NN)
                hout[(size_t)row * DIM + n * 16 + m] = (_Float16)acc[n][r];
        }
    }
}

// ---------------- fused conv: gather + on-the-fly norm + self + bias + L2norm/ReLU ----
__launch_bounds__(256, 8)
__global__ void conv_kernel(const half2v* __restrict__ h2, const float* __restrict__ bias,
                            const int* __restrict__ cnt, const unsigned short* __restrict__ edges,
                            const float* __restrict__ dq, const float* __restrict__ selfn,
                            half2v* __restrict__ out, const int* __restrict__ batch,
                            float* __restrict__ pooled, int do_pool) {
    int wid = threadIdx.x >> 6;
    int lane = threadIdx.x & 63;
    int node = blockIdx.x * 4 + wid;
    if (node >= NN) return;
    int deg = cnt[node];
    const unsigned short* ep = edges + (size_t)node * MAXD;   // 384B rows, 16B-aligned
    float ax = 0.f, ay = 0.f;
    int e = 0;
    for (; e + 8 <= deg; e += 8) {
        vuint4 pk = __builtin_nontemporal_load((const vuint4*)(ep + e));
        unsigned s0 = pk.x & 0xFFFFu, s1 = pk.x >> 16;
        unsigned s2 = pk.y & 0xFFFFu, s3 = pk.y >> 16;
        unsigned s4 = pk.z & 0xFFFFu, s5 = pk.z >> 16;
        unsigned s6 = pk.w & 0xFFFFu, s7 = pk.w >> 16;
        float d0 = dq[s0], d1 = dq[s1], d2 = dq[s2], d3 = dq[s3];
        float d4 = dq[s4], d5 = dq[s5], d6 = dq[s6], d7 = dq[s7];
        half2v v0 = h2[(size_t)s0 * 64 + lane];
        half2v v1 = h2[(size_t)s1 * 64 + lane];
        half2v v2 = h2[(size_t)s2 * 64 + lane];
        half2v v3 = h2[(size_t)s3 * 64 + lane];
        half2v v4 = h2[(size_t)s4 * 64 + lane];
        half2v v5 = h2[(size_t)s5 * 64 + lane];
        half2v v6 = h2[(size_t)s6 * 64 + lane];
        half2v v7 = h2[(size_t)s7 * 64 + lane];
        ax += d0 * (float)v0.x + d1 * (float)v1.x + d2 * (float)v2.x + d3 * (float)v3.x
            + d4 * (float)v4.x + d5 * (float)v5.x + d6 * (float)v6.x + d7 * (float)v7.x;
        ay += d0 * (float)v0.y + d1 * (float)v1.y + d2 * (float)v2.y + d3 * (float)v3.y
            + d4 * (float)v4.y + d5 * (float)v5.y + d6 * (float)v6.y + d7 * (float)v7.y;
    }
    for (; e < deg; ++e) {
        unsigned s = ep[e];
        float ds = dq[s];
        half2v v = h2[(size_t)s * 64 + lane];
        ax += ds * (float)v.x;
        ay += ds * (float)v.y;
    }
    float dqd = dq[node];
    float sn = selfn[node];
    half2v hv = h2[(size_t)node * 64 + lane];
    ax = ax * dqd + sn * (float)hv.x + bias[2 * lane];
    ay = ay * dqd + sn * (float)hv.y + bias[2 * lane + 1];
    float ss = ax * ax + ay * ay;
#pragma unroll
    for (int off = 32; off; off >>= 1) ss += __shfl_xor(ss, off);
    float inv = 1.0f / fmaxf(sqrtf(ss), 1e-12f);
    float ox = fmaxf(ax * inv, 0.f);
    float oy = fmaxf(ay * inv, 0.f);
    if (!do_pool) {
        half2v o;
        o.x = (_Float16)ox;
        o.y = (_Float16)oy;
        out[(size_t)node * 64 + lane] = o;   // cached: y stays L2-hot for next GEMM
    } else {
        int g = batch[node];
        atomicAdd(&pooled[g * DIM + 2 * lane], ox);
        atomicAdd(&pooled[g * DIM + 2 * lane + 1], oy);
    }
}

// ---------------- head: z = relu(pooled@W1+b1); logits = z@W2+b2 ----------------
__launch_bounds__(128)
__global__ void head_kernel(const float* __restrict__ pooled, const float* __restrict__ w1,
                            const float* __restrict__ b1, const float* __restrict__ w2,
                            const float* __restrict__ b2, float* __restrict__ out) {
    __shared__ float sp[DIM];
    __shared__ float red[4];
    int g = blockIdx.x;
    int k = threadIdx.x;
    sp[k] = pooled[g * DIM + k];
    __syncthreads();
    float acc = b1[k];
#pragma unroll 8
    for (int j = 0; j < DIM; ++j) acc += sp[j] * w1[j * DIM + k];
    float z = fmaxf(acc, 0.f);
    float p0 = z * w2[k * 2 + 0];
    float p1 = z * w2[k * 2 + 1];
#pragma unroll
    for (int off = 32; off; off >>= 1) {
        p0 += __shfl_xor(p0, off);
        p1 += __shfl_xor(p1, off);
    }
    if ((k & 63) == 0) {
        red[(k >> 6) * 2 + 0] = p0;
        red[(k >> 6) * 2 + 1] = p1;
    }
    __syncthreads();
    if (k == 0) {
        out[g * 2 + 0] = red[0] + red[2] + b2[0];
        out[g * 2 + 1] = red[1] + red[3] + b2[1];
    }
}

extern "C" void kernel_launch(void* const* d_in, const int* in_sizes, int n_in,
                              void* d_out, int out_size, void* d_ws, size_t ws_size,
                              hipStream_t stream) {
    const float* x    = (const float*)d_in[0];
    const int* eidx   = (const int*)d_in[1];
    const int* batch  = (const int*)d_in[2];
    const float* W0   = (const float*)d_in[3];
    const float* b0   = (const float*)d_in[4];
    const float* W1   = (const float*)d_in[5];
    const float* b1   = (const float*)d_in[6];
    const float* W2   = (const float*)d_in[7];
    const float* b2   = (const float*)d_in[8];
    const float* l1w  = (const float*)d_in[9];
    const float* l1b  = (const float*)d_in[10];
    const float* l2w  = (const float*)d_in[11];
    const float* l2b  = (const float*)d_in[12];
    float* out = (float*)d_out;

    char* w = (char*)d_ws;
    float* dq     = (float*)w; w += (size_t)NN * 4;
    float* selfn  = (float*)w; w += (size_t)NN * 4;
    int*   cursor = (int*)w;   w += (size_t)NN * 4;
    unsigned short* edges = (unsigned short*)w; w += (size_t)NN * MAXD * 2;  // 19.2 MB
    half8* wf     = (half8*)w; w += (size_t)3 * 2048 * 16;
    _Float16* bufh = (_Float16*)w; w += (size_t)NN * DIM * 2;   // h (gemm out, gathered)
    _Float16* bufy = (_Float16*)w; w += (size_t)NN * DIM * 2;   // y (conv out)
    float* pooled = (float*)w; w += (size_t)NG * DIM * 4;

    const int* src = eidx;
    const int* dst = eidx + NE;

    initcvt_kernel<<<3 + (NN + NG * DIM + 255) / 256, 256, 0, stream>>>(W0, W1, W2, wf,
                                                                        cursor, pooled);
    for (int p = 0; p < NPASS; ++p)
        scatter_kernel<<<(NE + 255) / 256, 256, 0, stream>>>(src, dst, cursor, edges,
                                                             p * PASSW, (p + 1) * PASSW);
    coeff_kernel<<<(NN + 255) / 256, 256, 0, stream>>>(cursor, dq, selfn);

    const int CG = (NN + 3) / 4;        // 12500 blocks, one wave per node
    const int GG = (NN + 63) / 64;      // 782 blocks, one 64-row group per block

    gemm0_mfma<<<GG, 256, 0, stream>>>(x, wf, bufh);
    conv_kernel<<<CG, 256, 0, stream>>>((const half2v*)bufh, b0, cursor, edges, dq, selfn,
                                        (half2v*)bufy, batch, pooled, 0);
    gemm_mfma<<<GG, 256, 0, stream>>>(bufy, wf + 2048, bufh);
    conv_kernel<<<CG, 256, 0, stream>>>((const half2v*)bufh, b1, cursor, edges, dq, selfn,
                                        (half2v*)bufy, batch, pooled, 0);
    gemm_mfma<<<GG, 256, 0, stream>>>(bufy, wf + 4096, bufh);
    conv_kernel<<<CG, 256, 0, stream>>>((const half2v*)bufh, b2, cursor, edges, dq, selfn,
                                        (half2v*)bufy, batch, pooled, 1);
    head_kernel<<<NG, 128, 0, stream>>>(pooled, l1w, l1b, l2w, l2b, out);
}

// Round 12
// 459.838 us; speedup vs baseline: 7.2873x; 1.0244x over previous
//
#include <hip/hip_runtime.h>

#define NN 50000
#define NE 1600000
#define DIM 128
#define NG  512
#define MAXD 192     // bucket capacity; Poisson(lambda=32), P(any deg>192) astronomically small

typedef int      vint4   __attribute__((ext_vector_type(4)));
typedef float    vfloat4 __attribute__((ext_vector_type(4)));
typedef float    floatx4 __attribute__((ext_vector_type(4)));
typedef unsigned vuint4  __attribute__((ext_vector_type(4)));
typedef _Float16 half2v  __attribute__((ext_vector_type(2)));
typedef _Float16 half8   __attribute__((ext_vector_type(8)));

__device__ __forceinline__ half8 cvt8(vfloat4 a, vfloat4 b) {
    half8 r;
    r[0] = (_Float16)a.x; r[1] = (_Float16)a.y; r[2] = (_Float16)a.z; r[3] = (_Float16)a.w;
    r[4] = (_Float16)b.x; r[5] = (_Float16)b.y; r[6] = (_Float16)b.z; r[7] = (_Float16)b.w;
    return r;
}

// ---------------- fused init: W->frag cvt | zero cursor+pooled ----------------
__global__ void initcvt_kernel(const float* __restrict__ W0, const float* __restrict__ W1,
                               const float* __restrict__ W2, half8* __restrict__ wf,
                               int* __restrict__ cursor, float* __restrict__ pooled) {
    int b = blockIdx.x;
    if (b < 3) {
        const float* Ws[3] = {W0, W1, W2};
        const float* W = Ws[b];
        half8* outp = wf + (size_t)b * 2048;
        for (int idx = threadIdx.x; idx < 2048; idx += 256) {
            int t = idx >> 9;
            int n = (idx >> 6) & 7;
            int ln = idx & 63;
            int q = ln >> 4, c = ln & 15;
            const float* wp = W + (t * 32 + q * 8) * DIM + n * 16 + c;
            half8 f;
#pragma unroll
            for (int j = 0; j < 8; ++j) f[j] = (_Float16)wp[j * DIM];
            outp[idx] = f;
        }
    } else {
        int k = (b - 3) * 256 + threadIdx.x;
        if (k < NN) cursor[k] = 0;
        else if (k < NN + NG * DIM) pooled[k - NN] = 0.f;
    }
}

// ---------------- scatter into TRANSPOSED buckets: et[pos*NN + d] ----------------
// Cursors advance ~uniformly -> concurrent writes concentrate in a few 100 KB
// slot-planes -> store RFOs hit L2, lines fill before writeback. 4 edges/thread
// for atomic-issue MLP.
__global__ void scatter_t(const int* __restrict__ src, const int* __restrict__ dst,
                          int* __restrict__ cursor, unsigned short* __restrict__ et) {
    int e0 = (blockIdx.x * blockDim.x + threadIdx.x) * 4;
    if (e0 >= NE) return;
    vint4 d4 = __builtin_nontemporal_load((const vint4*)(dst + e0));
    vint4 s4 = __builtin_nontemporal_load((const vint4*)(src + e0));
    int p0 = atomicAdd(&cursor[d4.x], 1);
    int p1 = atomicAdd(&cursor[d4.y], 1);
    int p2 = atomicAdd(&cursor[d4.z], 1);
    int p3 = atomicAdd(&cursor[d4.w], 1);
    et[(size_t)p0 * NN + d4.x] = (unsigned short)s4.x;
    et[(size_t)p1 * NN + d4.y] = (unsigned short)s4.y;
    et[(size_t)p2 * NN + d4.z] = (unsigned short)s4.z;
    et[(size_t)p3 * NN + d4.w] = (unsigned short)s4.w;
}

// ---------------- transpose planes -> row-major buckets, fused coeffs ----------------
// Reads et[p*NN+i]: consecutive threads read consecutive 2B -> fully coalesced.
__global__ void transpose_coeff(const unsigned short* __restrict__ et,
                                const int* __restrict__ cnt,
                                unsigned short* __restrict__ edges,
                                float* __restrict__ dq, float* __restrict__ selfn) {
    int i = blockIdx.x * 256 + threadIdx.x;
    if (i >= NN) return;
    int deg = cnt[i];
    unsigned short* row = edges + (size_t)i * MAXD;
    for (int p = 0; p < deg; ++p)
        row[p] = et[(size_t)p * NN + i];
    float dg = (float)(deg + 1);
    dq[i] = 1.0f / sqrtf(dg);
    selfn[i] = 1.0f / dg;
}

// ---------------- layer-0 GEMM: reads fp32 x directly, converts in-register ----------
__launch_bounds__(256, 2)
__global__ void gemm0_mfma(const float* __restrict__ x, const half8* __restrict__ wfl,
                           _Float16* __restrict__ hout) {
    __shared__ half8 Wf[2048];   // 32 KB
    int tid = threadIdx.x;
    for (int idx = tid; idx < 2048; idx += 256) Wf[idx] = wfl[idx];
    __syncthreads();
    int wid = tid >> 6, lane = tid & 63;
    int q = lane >> 4, m = lane & 15;
    int r0 = blockIdx.x * 64 + wid * 16;
    int arow = r0 + m;
    if (arow > NN - 1) arow = NN - 1;
    const vfloat4* ap = (const vfloat4*)(x + (size_t)arow * DIM + q * 8);
    half8 a0 = cvt8(ap[0],  ap[1]);     // k-step stride = 32 floats = 8 vfloat4
    half8 a1 = cvt8(ap[8],  ap[9]);
    half8 a2 = cvt8(ap[16], ap[17]);
    half8 a3 = cvt8(ap[24], ap[25]);
    floatx4 acc[8];
#pragma unroll
    for (int n = 0; n < 8; ++n) acc[n] = (floatx4){0.f, 0.f, 0.f, 0.f};
#pragma unroll
    for (int n = 0; n < 8; ++n)
        acc[n] = __builtin_amdgcn_mfma_f32_16x16x32_f16(a0, Wf[(0 * 8 + n) * 64 + lane], acc[n], 0, 0, 0);
#pragma unroll
    for (int n = 0; n < 8; ++n)
        acc[n] = __builtin_amdgcn_mfma_f32_16x16x32_f16(a1, Wf[(1 * 8 + n) * 64 + lane], acc[n], 0, 0, 0);
#pragma unroll
    for (int n = 0; n < 8; ++n)
        acc[n] = __builtin_amdgcn_mfma_f32_16x16x32_f16(a2, Wf[(2 * 8 + n) * 64 + lane], acc[n], 0, 0, 0);
#pragma unroll
    for (int n = 0; n < 8; ++n)
        acc[n] = __builtin_amdgcn_mfma_f32_16x16x32_f16(a3, Wf[(3 * 8 + n) * 64 + lane], acc[n], 0, 0, 0);
#pragma unroll
    for (int n = 0; n < 8; ++n) {
#pragma unroll
        for (int r = 0; r < 4; ++r) {
            int row = r0 + q * 4 + r;
            if (row < NN)
                hout[(size_t)row * DIM + n * 16 + m] = (_Float16)acc[n][r];
        }
    }
}

// ---------------- GEMM via MFMA: one 64-row group per block (fp16 input) ----------------
__launch_bounds__(256, 2)
__global__ void gemm_mfma(const _Float16* __restrict__ yin, const half8* __restrict__ wfl,
                          _Float16* __restrict__ hout) {
    __shared__ half8 Wf[2048];   // 32 KB
    int tid = threadIdx.x;
    for (int idx = tid; idx < 2048; idx += 256) Wf[idx] = wfl[idx];
    __syncthreads();
    int wid = tid >> 6, lane = tid & 63;
    int q = lane >> 4, m = lane & 15;
    int r0 = blockIdx.x * 64 + wid * 16;
    int arow = r0 + m;
    if (arow > NN - 1) arow = NN - 1;
    const half8* ap = (const half8*)(yin + (size_t)arow * DIM + q * 8);
    half8 a0 = ap[0], a1 = ap[4], a2 = ap[8], a3 = ap[12];
    floatx4 acc[8];
#pragma unroll
    for (int n = 0; n < 8; ++n) acc[n] = (floatx4){0.f, 0.f, 0.f, 0.f};
#pragma unroll
    for (int n = 0; n < 8; ++n)
        acc[n] = __builtin_amdgcn_mfma_f32_16x16x32_f16(a0, Wf[(0 * 8 + n) * 64 + lane], acc[n], 0, 0, 0);
#pragma unroll
    for (int n = 0; n < 8; ++n)
        acc[n] = __builtin_amdgcn_mfma_f32_16x16x32_f16(a1, Wf[(1 * 8 + n) * 64 + lane], acc[n], 0, 0, 0);
#pragma unroll
    for (int n = 0; n < 8; ++n)
        acc[n] = __builtin_amdgcn_mfma_f32_16x16x32_f16(a2, Wf[(2 * 8 + n) * 64 + lane], acc[n], 0, 0, 0);
#pragma unroll
    for (int n = 0; n < 8; ++n)
        acc[n] = __builtin_amdgcn_mfma_f32_16x16x32_f16(a3, Wf[(3 * 8 + n) * 64 + lane], acc[n], 0, 0, 0);
#pragma unroll
    for (int n = 0; n < 8; ++n) {
#pragma unroll
        for (int r = 0; r < 4; ++r) {
            int row = r0 + q * 4 + r;
            if (row < NN)
                hout[(size_t)row * DIM + n * 16 + m] = (_Float16)acc[n][r];
        }
    }
}

// ---------------- fused conv: gather + on-the-fly norm + self + bias + L2norm/ReLU ----
__launch_bounds__(256, 8)
__global__ void conv_kernel(const half2v* __restrict__ h2, const float* __restrict__ bias,
                            const int* __restrict__ cnt, const unsigned short* __restrict__ edges,
                            const float* __restrict__ dq, const float* __restrict__ selfn,
                            half2v* __restrict__ out, const int* __restrict__ batch,
                            float* __restrict__ pooled, int do_pool) {
    int wid = threadIdx.x >> 6;
    int lane = threadIdx.x & 63;
    int node = blockIdx.x * 4 + wid;
    if (node >= NN) return;
    int deg = cnt[node];
    const unsigned short* ep = edges + (size_t)node * MAXD;   // 384B rows, 16B-aligned
    float ax = 0.f, ay = 0.f;
    int e = 0;
    for (; e + 8 <= deg; e += 8) {
        vuint4 pk = __builtin_nontemporal_load((const vuint4*)(ep + e));
        unsigned s0 = pk.x & 0xFFFFu, s1 = pk.x >> 16;
        unsigned s2 = pk.y & 0xFFFFu, s3 = pk.y >> 16;
        unsigned s4 = pk.z & 0xFFFFu, s5 = pk.z >> 16;
        unsigned s6 = pk.w & 0xFFFFu, s7 = pk.w >> 16;
        float d0 = dq[s0], d1 = dq[s1], d2 = dq[s2], d3 = dq[s3];
        float d4 = dq[s4], d5 = dq[s5], d6 = dq[s6], d7 = dq[s7];
        half2v v0 = h2[(size_t)s0 * 64 + lane];
        half2v v1 = h2[(size_t)s1 * 64 + lane];
        half2v v2 = h2[(size_t)s2 * 64 + lane];
        half2v v3 = h2[(size_t)s3 * 64 + lane];
        half2v v4 = h2[(size_t)s4 * 64 + lane];
        half2v v5 = h2[(size_t)s5 * 64 + lane];
        half2v v6 = h2[(size_t)s6 * 64 + lane];
        half2v v7 = h2[(size_t)s7 * 64 + lane];
        ax += d0 * (float)v0.x + d1 * (float)v1.x + d2 * (float)v2.x + d3 * (float)v3.x
            + d4 * (float)v4.x + d5 * (float)v5.x + d6 * (float)v6.x + d7 * (float)v7.x;
        ay += d0 * (float)v0.y + d1 * (float)v1.y + d2 * (float)v2.y + d3 * (float)v3.y
            + d4 * (float)v4.y + d5 * (float)v5.y + d6 * (float)v6.y + d7 * (float)v7.y;
    }
    for (; e < deg; ++e) {
        unsigned s = ep[e];
        float ds = dq[s];
        half2v v = h2[(size_t)s * 64 + lane];
        ax += ds * (float)v.x;
        ay += ds * (float)v.y;
    }
    float dqd = dq[node];
    float sn = selfn[node];
    half2v hv = h2[(size_t)node * 64 + lane];
    ax = ax * dqd + sn * (float)hv.x + bias[2 * lane];
    ay = ay * dqd + sn * (float)hv.y + bias[2 * lane + 1];
    float ss = ax * ax + ay * ay;
#pragma unroll
    for (int off = 32; off; off >>= 1) ss += __shfl_xor(ss, off);
    float inv = 1.0f / fmaxf(sqrtf(ss), 1e-12f);
    float ox = fmaxf(ax * inv, 0.f);
    float oy = fmaxf(ay * inv, 0.f);
    if (!do_pool) {
        half2v o;
        o.x = (_Float16)ox;
        o.y = (_Float16)oy;
        out[(size_t)node * 64 + lane] = o;   // cached: y stays L2-hot for next GEMM
    } else {
        int g = batch[node];
        atomicAdd(&pooled[g * DIM + 2 * lane], ox);
        atomicAdd(&pooled[g * DIM + 2 * lane + 1], oy);
    }
}

// ---------------- head: z = relu(pooled@W1+b1); logits = z@W2+b2 ----------------
__launch_bounds__(128)
__global__ void head_kernel(const float* __restrict__ pooled, const float* __restrict__ w1,
                            const float* __restrict__ b1, const float* __restrict__ w2,
                            const float* __restrict__ b2, float* __restrict__ out) {
    __shared__ float sp[DIM];
    __shared__ float red[4];
    int g = blockIdx.x;
    int k = threadIdx.x;
    sp[k] = pooled[g * DIM + k];
    __syncthreads();
    float acc = b1[k];
#pragma unroll 8
    for (int j = 0; j < DIM; ++j) acc += sp[j] * w1[j * DIM + k];
    float z = fmaxf(acc, 0.f);
    float p0 = z * w2[k * 2 + 0];
    float p1 = z * w2[k * 2 + 1];
#pragma unroll
    for (int off = 32; off; off >>= 1) {
        p0 += __shfl_xor(p0, off);
        p1 += __shfl_xor(p1, off);
    }
    if ((k & 63) == 0) {
        red[(k >> 6) * 2 + 0] = p0;
        red[(k >> 6) * 2 + 1] = p1;
    }
    __syncthreads();
    if (k == 0) {
        out[g * 2 + 0] = red[0] + red[2] + b2[0];
        out[g * 2 + 1] = red[1] + red[3] + b2[1];
    }
}

extern "C" void kernel_launch(void* const* d_in, const int* in_sizes, int n_in,
                              void* d_out, int out_size, void* d_ws, size_t ws_size,
                              hipStream_t stream) {
    const float* x    = (const float*)d_in[0];
    const int* eidx   = (const int*)d_in[1];
    const int* batch  = (const int*)d_in[2];
    const float* W0   = (const float*)d_in[3];
    const float* b0   = (const float*)d_in[4];
    const float* W1   = (const float*)d_in[5];
    const float* b1   = (const float*)d_in[6];
    const float* W2   = (const float*)d_in[7];
    const float* b2   = (const float*)d_in[8];
    const float* l1w  = (const float*)d_in[9];
    const float* l1b  = (const float*)d_in[10];
    const float* l2w  = (const float*)d_in[11];
    const float* l2b  = (const float*)d_in[12];
    float* out = (float*)d_out;

    char* w = (char*)d_ws;
    float* dq     = (float*)w; w += (size_t)NN * 4;
    float* selfn  = (float*)w; w += (size_t)NN * 4;
    int*   cursor = (int*)w;   w += (size_t)NN * 4;
    unsigned short* edges = (unsigned short*)w; w += (size_t)NN * MAXD * 2;  // 19.2 MB
    unsigned short* et    = (unsigned short*)w; w += (size_t)NN * MAXD * 2;  // 19.2 MB
    half8* wf     = (half8*)w; w += (size_t)3 * 2048 * 16;
    _Float16* bufh = (_Float16*)w; w += (size_t)NN * DIM * 2;   // h (gemm out, gathered)
    _Float16* bufy = (_Float16*)w; w += (size_t)NN * DIM * 2;   // y (conv out)
    float* pooled = (float*)w; w += (size_t)NG * DIM * 4;

    const int* src = eidx;
    const int* dst = eidx + NE;

    initcvt_kernel<<<3 + (NN + NG * DIM + 255) / 256, 256, 0, stream>>>(W0, W1, W2, wf,
                                                                        cursor, pooled);
    scatter_t<<<(NE / 4 + 255) / 256, 256, 0, stream>>>(src, dst, cursor, et);
    transpose_coeff<<<(NN + 255) / 256, 256, 0, stream>>>(et, cursor, edges, dq, selfn);

    const int CG = (NN + 3) / 4;        // 12500 blocks, one wave per node
    const int GG = (NN + 63) / 64;      // 782 blocks, one 64-row group per block

    gemm0_mfma<<<GG, 256, 0, stream>>>(x, wf, bufh);
    conv_kernel<<<CG, 256, 0, stream>>>((const half2v*)bufh, b0, cursor, edges, dq, selfn,
                                        (half2v*)bufy, batch, pooled, 0);
    gemm_mfma<<<GG, 256, 0, stream>>>(bufy, wf + 2048, bufh);
    conv_kernel<<<CG, 256, 0, stream>>>((const half2v*)bufh, b1, cursor, edges, dq, selfn,
                                        (half2v*)bufy, batch, pooled, 0);
    gemm_mfma<<<GG, 256, 0, stream>>>(bufy, wf + 4096, bufh);
    conv_kernel<<<CG, 256, 0, stream>>>((const half2v*)bufh, b2, cursor, edges, dq, selfn,
                                        (half2v*)bufy, batch, pooled, 1);
    head_kernel<<<NG, 128, 0, stream>>>(pooled, l1w, l1b, l2w, l2b, out);
}